// Round 1
// baseline (2764.522 us; speedup 1.0000x reference)
//
#include <hip/hip_runtime.h>
#include <math.h>

#define B_SZ    2
#define L_SEQ   2048
#define D_MODEL 1024
#define D_INNER 2048
#define D_STATE 16
#define DT_RANK 64
#define D_CONV  4
#define MM      (B_SZ * L_SEQ)   // 4096 rows

// ---------------------------------------------------------------------------
// Generic tiled fp32 GEMM: C[M,N] = A[M,K] @ B[K,N], row-major w/ leading dims.
// 64x64 block tile, 256 threads, 4x4 per thread, K-tile 16.
// M, N multiples of 64; K multiple of 16 (true for all call sites).
// ---------------------------------------------------------------------------
__global__ __launch_bounds__(256) void gemm_f32(const float* __restrict__ A,
                                                const float* __restrict__ B,
                                                float* __restrict__ C,
                                                int M, int N, int K,
                                                int lda, int ldb, int ldc) {
    __shared__ float As[16][68];  // [k][m], padded for 16B-aligned float4 reads
    __shared__ float Bs[16][68];  // [k][n]
    const int tx = threadIdx.x & 15;
    const int ty = threadIdx.x >> 4;
    const int bm = blockIdx.y * 64;
    const int bn = blockIdx.x * 64;

    float acc[4][4] = {};

    for (int k0 = 0; k0 < K; k0 += 16) {
        #pragma unroll
        for (int i = 0; i < 4; ++i) {
            int idx = threadIdx.x + i * 256;   // 0..1023
            int r = idx >> 4, c = idx & 15;    // A tile 64 rows x 16 cols
            As[c][r] = A[(size_t)(bm + r) * lda + (k0 + c)];
        }
        #pragma unroll
        for (int i = 0; i < 4; ++i) {
            int idx = threadIdx.x + i * 256;
            int r = idx >> 6, c = idx & 63;    // B tile 16 rows x 64 cols
            Bs[r][c] = B[(size_t)(k0 + r) * ldb + (bn + c)];
        }
        __syncthreads();
        #pragma unroll
        for (int k = 0; k < 16; ++k) {
            float4 av = *(const float4*)&As[k][ty * 4];
            float4 bv = *(const float4*)&Bs[k][tx * 4];
            float a[4] = {av.x, av.y, av.z, av.w};
            float b[4] = {bv.x, bv.y, bv.z, bv.w};
            #pragma unroll
            for (int i = 0; i < 4; ++i)
                #pragma unroll
                for (int j = 0; j < 4; ++j)
                    acc[i][j] += a[i] * b[j];
        }
        __syncthreads();
    }

    #pragma unroll
    for (int i = 0; i < 4; ++i) {
        int row = bm + ty * 4 + i;
        float4 v = make_float4(acc[i][0], acc[i][1], acc[i][2], acc[i][3]);
        *(float4*)&C[(size_t)row * ldc + bn + tx * 4] = v;
    }
}

// ---------------------------------------------------------------------------
// Depthwise causal conv (k=4) + bias + SiLU.
// xr holds [xs | res] rows of width 4096; xs = columns 0..2047.
// ---------------------------------------------------------------------------
__global__ __launch_bounds__(256) void conv_silu(const float* __restrict__ xr,
                                                 const float* __restrict__ cw,
                                                 const float* __restrict__ cb,
                                                 float* __restrict__ xc) {
    int idx = blockIdx.x * 256 + threadIdx.x;  // MM*2048 threads
    int d = idx & (D_INNER - 1);
    int m = idx >> 11;
    int l = m & (L_SEQ - 1);
    float acc = cb[d];
    #pragma unroll
    for (int k = 0; k < 4; ++k) {
        int ll = l - 3 + k;
        if (ll >= 0)
            acc += xr[(size_t)(m - 3 + k) * 4096 + d] * cw[d * 4 + k];
    }
    float s = acc / (1.f + __expf(-acc));  // silu
    xc[idx] = s;
}

// ---------------------------------------------------------------------------
// Per row m: x_dbl = xc_row @ W_x (96 outs), then
// delta = softplus(x_dbl[:64] @ W_dt + b_dt) (2048 outs), plus write B, C.
// One block (256 threads) per row.
// ---------------------------------------------------------------------------
__global__ __launch_bounds__(256) void xdbl_delta(const float* __restrict__ xc,
                                                  const float* __restrict__ W_x,
                                                  const float* __restrict__ W_dt,
                                                  const float* __restrict__ b_dt,
                                                  float* __restrict__ delta,
                                                  float* __restrict__ Bm,
                                                  float* __restrict__ Cm) {
    __shared__ float row[D_INNER];
    __shared__ float xd[96];
    const int m = blockIdx.x;
    const int t = threadIdx.x;
    const float* xrow = xc + (size_t)m * D_INNER;
    for (int i = t; i < D_INNER; i += 256) row[i] = xrow[i];
    __syncthreads();

    if (t < 96) {
        float a0 = 0.f, a1 = 0.f, a2 = 0.f, a3 = 0.f;
        for (int k = 0; k < D_INNER; k += 4) {
            a0 += row[k + 0] * W_x[(size_t)(k + 0) * 96 + t];
            a1 += row[k + 1] * W_x[(size_t)(k + 1) * 96 + t];
            a2 += row[k + 2] * W_x[(size_t)(k + 2) * 96 + t];
            a3 += row[k + 3] * W_x[(size_t)(k + 3) * 96 + t];
        }
        xd[t] = (a0 + a1) + (a2 + a3);
    }
    __syncthreads();

    if (t < D_STATE) {
        Bm[(size_t)m * D_STATE + t] = xd[DT_RANK + t];
        Cm[(size_t)m * D_STATE + t] = xd[DT_RANK + D_STATE + t];
    }

    #pragma unroll
    for (int i = 0; i < 8; ++i) {
        int d = t + i * 256;
        float acc = b_dt[d];
        #pragma unroll
        for (int r = 0; r < DT_RANK; ++r)
            acc += xd[r] * W_dt[r * D_INNER + d];
        float sp = (acc > 20.f) ? acc : log1pf(__expf(acc));
        delta[(size_t)m * D_INNER + d] = sp;
    }
}

// ---------------------------------------------------------------------------
// Sequential selective scan. One thread per (b,d); 16 states in registers.
// B/C staged in LDS in chunks of 64 timesteps. Fuses +xc*D and *silu(res).
// Writes gated y into xr columns 0..2047 (xs half, dead after conv).
// ---------------------------------------------------------------------------
__global__ __launch_bounds__(256) void scan_kernel(const float* __restrict__ delta,
                                                   const float* __restrict__ xc,
                                                   const float* __restrict__ Bm,
                                                   const float* __restrict__ Cm,
                                                   const float* __restrict__ A_log,
                                                   const float* __restrict__ Dp,
                                                   float* __restrict__ xr) {
    const int b = blockIdx.y;
    const int d = blockIdx.x * 256 + threadIdx.x;

    float An[D_STATE];
    #pragma unroll
    for (int n = 0; n < D_STATE; ++n)
        An[n] = -__expf(A_log[(size_t)d * D_STATE + n]);
    const float Dv = Dp[d];

    float h[D_STATE];
    #pragma unroll
    for (int n = 0; n < D_STATE; ++n) h[n] = 0.f;

    __shared__ float sB[64][D_STATE];
    __shared__ float sC[64][D_STATE];

    for (int lc = 0; lc < L_SEQ; lc += 64) {
        __syncthreads();
        for (int i = threadIdx.x; i < 64 * D_STATE; i += 256) {
            int ll = i >> 4, n = i & 15;
            size_t src = ((size_t)b * L_SEQ + lc + ll) * D_STATE + n;
            sB[ll][n] = Bm[src];
            sC[ll][n] = Cm[src];
        }
        __syncthreads();

        for (int j = 0; j < 64; ++j) {
            int l = lc + j;
            size_t off = ((size_t)b * L_SEQ + l) * D_INNER + d;
            float dv  = delta[off];
            float xv  = xc[off];
            float dbx = dv * xv;
            float y = 0.f;
            #pragma unroll
            for (int n = 0; n < D_STATE; ++n) {
                float dA = __expf(dv * An[n]);
                h[n] = dA * h[n] + dbx * sB[j][n];
                y += h[n] * sC[j][n];
            }
            size_t rowoff = ((size_t)b * L_SEQ + l) * 4096;
            float resv = xr[rowoff + 2048 + d];
            float sres = resv / (1.f + __expf(-resv));
            float yg = (y + xv * Dv) * sres;
            xr[rowoff + d] = yg;
        }
    }
}

extern "C" void kernel_launch(void* const* d_in, const int* in_sizes, int n_in,
                              void* d_out, int out_size, void* d_ws, size_t ws_size,
                              hipStream_t stream) {
    const float* x      = (const float*)d_in[0];
    const float* W_in   = (const float*)d_in[1];
    const float* conv_w = (const float*)d_in[2];
    const float* conv_b = (const float*)d_in[3];
    const float* W_x    = (const float*)d_in[4];
    const float* W_dt   = (const float*)d_in[5];
    const float* b_dt   = (const float*)d_in[6];
    const float* A_log  = (const float*)d_in[7];
    const float* D_par  = (const float*)d_in[8];
    const float* W_out  = (const float*)d_in[9];
    float* out = (float*)d_out;

    float* ws    = (float*)d_ws;
    float* xr    = ws;                          // MM*4096 = 16,777,216 floats
    float* xc    = xr + (size_t)MM * 4096;      // MM*2048
    float* delta = xc + (size_t)MM * D_INNER;   // MM*2048
    float* Bbuf  = delta + (size_t)MM * D_INNER;// MM*16
    float* Cbuf  = Bbuf + (size_t)MM * D_STATE; // MM*16

    dim3 blk(256);

    // K1: xr = x @ W_in   (M=4096, N=4096, K=1024)
    gemm_f32<<<dim3(4096 / 64, 4096 / 64), blk, 0, stream>>>(
        x, W_in, xr, MM, 2 * D_INNER, D_MODEL, D_MODEL, 2 * D_INNER, 2 * D_INNER);

    // K2: xc = silu(conv(xs) + b)
    conv_silu<<<dim3((size_t)MM * D_INNER / 256), blk, 0, stream>>>(xr, conv_w, conv_b, xc);

    // K3: x_dbl, delta, B, C
    xdbl_delta<<<dim3(MM), blk, 0, stream>>>(xc, W_x, W_dt, b_dt, delta, Bbuf, Cbuf);

    // K4: selective scan + gating, writes y into xr[:, 0:2048]
    scan_kernel<<<dim3(D_INNER / 256, B_SZ), blk, 0, stream>>>(
        delta, xc, Bbuf, Cbuf, A_log, D_par, xr);

    // K5: out = y @ W_out  (M=4096, N=1024, K=2048); A = xr with lda=4096
    gemm_f32<<<dim3(1024 / 64, 4096 / 64), blk, 0, stream>>>(
        xr, W_out, out, MM, D_MODEL, D_INNER, 4096, D_MODEL, D_MODEL);
}

// Round 2
// 1588.602 us; speedup vs baseline: 1.7402x; 1.7402x over previous
//
#include <hip/hip_runtime.h>
#include <math.h>

#define B_SZ    2
#define L_SEQ   2048
#define D_MODEL 1024
#define D_INNER 2048
#define D_STATE 16
#define DT_RANK 64
#define D_CONV  4
#define MM      (B_SZ * L_SEQ)   // 4096 rows

// ---------------------------------------------------------------------------
// Tiled fp32 GEMM: C[M,N] = A[M,K] @ B[K,N], row-major w/ leading dims.
// 128x128 block tile, 256 threads, 8x8 per thread, K-tile 8, reg-prefetch.
// M, N multiples of 128; K multiple of 8 (true for all call sites).
// ---------------------------------------------------------------------------
__global__ __launch_bounds__(256) void gemm_f32(const float* __restrict__ A,
                                                const float* __restrict__ B,
                                                float* __restrict__ C,
                                                int M, int N, int K,
                                                int lda, int ldb, int ldc) {
    __shared__ float As[8][132];  // [k][m]; 132*4B=528B row -> 16B aligned
    __shared__ float Bs[8][132];  // [k][n]
    const int tx = threadIdx.x & 15;
    const int ty = threadIdx.x >> 4;
    const int bm = blockIdx.y * 128;
    const int bn = blockIdx.x * 128;

    const int ar = threadIdx.x >> 1;          // 0..127 (A tile row)
    const int ac = (threadIdx.x & 1) * 4;     // 0 or 4 (A tile col group)
    const int br = threadIdx.x >> 5;          // 0..7   (B tile row)
    const int bc = (threadIdx.x & 31) * 4;    // 0..124 (B tile col group)

    float acc[8][8] = {};

    float4 av = *(const float4*)&A[(size_t)(bm + ar) * lda + ac];
    float4 bv = *(const float4*)&B[(size_t)br * ldb + bn + bc];

    for (int k0 = 0; k0 < K; k0 += 8) {
        As[ac + 0][ar] = av.x;
        As[ac + 1][ar] = av.y;
        As[ac + 2][ar] = av.z;
        As[ac + 3][ar] = av.w;
        *(float4*)&Bs[br][bc] = bv;
        __syncthreads();

        if (k0 + 8 < K) {  // prefetch next tile while computing this one
            av = *(const float4*)&A[(size_t)(bm + ar) * lda + (k0 + 8) + ac];
            bv = *(const float4*)&B[(size_t)(k0 + 8 + br) * ldb + bn + bc];
        }

        #pragma unroll
        for (int k = 0; k < 8; ++k) {
            float4 a0 = *(const float4*)&As[k][ty * 4];
            float4 a1 = *(const float4*)&As[k][64 + ty * 4];
            float4 b0 = *(const float4*)&Bs[k][tx * 4];
            float4 b1 = *(const float4*)&Bs[k][64 + tx * 4];
            float a[8]  = {a0.x, a0.y, a0.z, a0.w, a1.x, a1.y, a1.z, a1.w};
            float bb[8] = {b0.x, b0.y, b0.z, b0.w, b1.x, b1.y, b1.z, b1.w};
            #pragma unroll
            for (int i = 0; i < 8; ++i)
                #pragma unroll
                for (int j = 0; j < 8; ++j)
                    acc[i][j] += a[i] * bb[j];
        }
        __syncthreads();
    }

    #pragma unroll
    for (int i = 0; i < 8; ++i) {
        int row = bm + ((i < 4) ? (ty * 4 + i) : (64 + ty * 4 + i - 4));
        float4 v0 = make_float4(acc[i][0], acc[i][1], acc[i][2], acc[i][3]);
        float4 v1 = make_float4(acc[i][4], acc[i][5], acc[i][6], acc[i][7]);
        *(float4*)&C[(size_t)row * ldc + bn + tx * 4] = v0;
        *(float4*)&C[(size_t)row * ldc + bn + 64 + tx * 4] = v1;
    }
}

// ---------------------------------------------------------------------------
// Depthwise causal conv (k=4) + bias + SiLU.
// xr holds [xs | res] rows of width 4096; xs = columns 0..2047.
// ---------------------------------------------------------------------------
__global__ __launch_bounds__(256) void conv_silu(const float* __restrict__ xr,
                                                 const float* __restrict__ cw,
                                                 const float* __restrict__ cb,
                                                 float* __restrict__ xc) {
    int idx = blockIdx.x * 256 + threadIdx.x;  // MM*2048 threads
    int d = idx & (D_INNER - 1);
    int m = idx >> 11;
    int l = m & (L_SEQ - 1);
    float acc = cb[d];
    #pragma unroll
    for (int k = 0; k < 4; ++k) {
        int ll = l - 3 + k;
        if (ll >= 0)
            acc += xr[(size_t)(m - 3 + k) * 4096 + d] * cw[d * 4 + k];
    }
    float s = acc / (1.f + __expf(-acc));  // silu
    xc[idx] = s;
}

// ---------------------------------------------------------------------------
// Per row m: x_dbl = xc_row @ W_x (96 outs), then
// delta = softplus(x_dbl[:64] @ W_dt + b_dt) (2048 outs), plus write B, C.
// One block (256 threads) per row.
// ---------------------------------------------------------------------------
__global__ __launch_bounds__(256) void xdbl_delta(const float* __restrict__ xc,
                                                  const float* __restrict__ W_x,
                                                  const float* __restrict__ W_dt,
                                                  const float* __restrict__ b_dt,
                                                  float* __restrict__ delta,
                                                  float* __restrict__ Bm,
                                                  float* __restrict__ Cm) {
    __shared__ float row[D_INNER];
    __shared__ float xd[96];
    const int m = blockIdx.x;
    const int t = threadIdx.x;
    const float* xrow = xc + (size_t)m * D_INNER;
    for (int i = t; i < D_INNER; i += 256) row[i] = xrow[i];
    __syncthreads();

    if (t < 96) {
        float a0 = 0.f, a1 = 0.f, a2 = 0.f, a3 = 0.f;
        for (int k = 0; k < D_INNER; k += 4) {
            a0 += row[k + 0] * W_x[(size_t)(k + 0) * 96 + t];
            a1 += row[k + 1] * W_x[(size_t)(k + 1) * 96 + t];
            a2 += row[k + 2] * W_x[(size_t)(k + 2) * 96 + t];
            a3 += row[k + 3] * W_x[(size_t)(k + 3) * 96 + t];
        }
        xd[t] = (a0 + a1) + (a2 + a3);
    }
    __syncthreads();

    if (t < D_STATE) {
        Bm[(size_t)m * D_STATE + t] = xd[DT_RANK + t];
        Cm[(size_t)m * D_STATE + t] = xd[DT_RANK + D_STATE + t];
    }

    #pragma unroll
    for (int i = 0; i < 8; ++i) {
        int d = t + i * 256;
        float acc = b_dt[d];
        #pragma unroll
        for (int r = 0; r < DT_RANK; ++r)
            acc += xd[r] * W_dt[r * D_INNER + d];
        float sp = (acc > 20.f) ? acc : log1pf(__expf(acc));
        delta[(size_t)m * D_INNER + d] = sp;
    }
}

// ---------------------------------------------------------------------------
// Selective scan, n-parallel: one thread per (b, d, n) recurrence.
// Block = 256 threads = 16 d-channels x 16 states. Grid = (D_INNER/16, B).
// y[l,d] = sum_n h[l,d,n]*C[l,n] via 4-step shfl_xor over the 16-lane group.
// delta/xc/B/C/res staged in LDS per 64-step chunk (coalesced float4 loads).
// Fuses +xc*D and *silu(res); writes gated y into xr columns 0..2047.
// ---------------------------------------------------------------------------
#define CH 64
__global__ __launch_bounds__(256) void scan_kernel(const float* __restrict__ delta,
                                                   const float* __restrict__ xc,
                                                   const float* __restrict__ Bm,
                                                   const float* __restrict__ Cm,
                                                   const float* __restrict__ A_log,
                                                   const float* __restrict__ Dp,
                                                   float* __restrict__ xr) {
    const int b  = blockIdx.y;
    const int n  = threadIdx.x & 15;
    const int dg = threadIdx.x >> 4;          // 0..15
    const int d0 = blockIdx.x * 16;
    const int d  = d0 + dg;

    const float An = -__expf(A_log[(size_t)d * D_STATE + n]);  // coalesced: d*16+n = d0*16+tid
    const float Dv = Dp[d];
    float h = 0.f;

    __shared__ float sD[CH][16];
    __shared__ float sX[CH][16];
    __shared__ float sB[CH][16];
    __shared__ float sC[CH][16];
    __shared__ float sR[CH][16];

    const int lj  = threadIdx.x >> 2;         // 0..63  (chunk-local timestep)
    const int ld4 = (threadIdx.x & 3) * 4;    // 0,4,8,12

    for (int lc = 0; lc < L_SEQ; lc += CH) {
        __syncthreads();
        {
            size_t row = (size_t)b * L_SEQ + lc + lj;
            *(float4*)&sD[lj][ld4] = *(const float4*)&delta[row * D_INNER + d0 + ld4];
            *(float4*)&sX[lj][ld4] = *(const float4*)&xc[row * D_INNER + d0 + ld4];
            *(float4*)&sB[lj][ld4] = *(const float4*)&Bm[row * D_STATE + ld4];
            *(float4*)&sC[lj][ld4] = *(const float4*)&Cm[row * D_STATE + ld4];
            *(float4*)&sR[lj][ld4] = *(const float4*)&xr[row * 4096 + 2048 + d0 + ld4];
        }
        __syncthreads();

        for (int j = 0; j < CH; ++j) {
            float dv = sD[j][dg];   // broadcast across 16 n-lanes: conflict-free
            float xv = sX[j][dg];
            float bv = sB[j][n];
            float cv = sC[j][n];
            h = __expf(dv * An) * h + (dv * xv) * bv;
            float yc = h * cv;
            yc += __shfl_xor(yc, 8, 16);
            yc += __shfl_xor(yc, 4, 16);
            yc += __shfl_xor(yc, 2, 16);
            yc += __shfl_xor(yc, 1, 16);
            if (n == 0) {
                float resv = sR[j][dg];
                float sres = resv / (1.f + __expf(-resv));
                size_t row = (size_t)b * L_SEQ + lc + j;
                xr[row * 4096 + d] = (yc + xv * Dv) * sres;
            }
        }
    }
}

extern "C" void kernel_launch(void* const* d_in, const int* in_sizes, int n_in,
                              void* d_out, int out_size, void* d_ws, size_t ws_size,
                              hipStream_t stream) {
    const float* x      = (const float*)d_in[0];
    const float* W_in   = (const float*)d_in[1];
    const float* conv_w = (const float*)d_in[2];
    const float* conv_b = (const float*)d_in[3];
    const float* W_x    = (const float*)d_in[4];
    const float* W_dt   = (const float*)d_in[5];
    const float* b_dt   = (const float*)d_in[6];
    const float* A_log  = (const float*)d_in[7];
    const float* D_par  = (const float*)d_in[8];
    const float* W_out  = (const float*)d_in[9];
    float* out = (float*)d_out;

    float* ws    = (float*)d_ws;
    float* xr    = ws;                          // MM*4096 floats
    float* xc    = xr + (size_t)MM * 4096;      // MM*2048
    float* delta = xc + (size_t)MM * D_INNER;   // MM*2048
    float* Bbuf  = delta + (size_t)MM * D_INNER;// MM*16
    float* Cbuf  = Bbuf + (size_t)MM * D_STATE; // MM*16

    dim3 blk(256);

    // K1: xr = x @ W_in   (M=4096, N=4096, K=1024)
    gemm_f32<<<dim3(4096 / 128, 4096 / 128), blk, 0, stream>>>(
        x, W_in, xr, MM, 2 * D_INNER, D_MODEL, D_MODEL, 2 * D_INNER, 2 * D_INNER);

    // K2: xc = silu(conv(xs) + b)
    conv_silu<<<dim3((size_t)MM * D_INNER / 256), blk, 0, stream>>>(xr, conv_w, conv_b, xc);

    // K3: x_dbl, delta, B, C
    xdbl_delta<<<dim3(MM), blk, 0, stream>>>(xc, W_x, W_dt, b_dt, delta, Bbuf, Cbuf);

    // K4: selective scan + gating, writes y into xr[:, 0:2048]
    scan_kernel<<<dim3(D_INNER / 16, B_SZ), blk, 0, stream>>>(
        delta, xc, Bbuf, Cbuf, A_log, D_par, xr);

    // K5: out = y @ W_out  (M=4096, N=1024, K=2048); A = xr with lda=4096
    gemm_f32<<<dim3(1024 / 128, 4096 / 128), blk, 0, stream>>>(
        xr, W_out, out, MM, D_MODEL, D_INNER, 4096, D_MODEL, D_MODEL);
}

// Round 3
// 584.383 us; speedup vs baseline: 4.7307x; 2.7184x over previous
//
#include <hip/hip_runtime.h>
#include <math.h>

#define B_SZ    2
#define L_SEQ   2048
#define D_MODEL 1024
#define D_INNER 2048
#define D_STATE 16
#define DT_RANK 64
#define MM      (B_SZ * L_SEQ)   // 4096 rows
#define NCH     32               // scan chunks
#define CLEN    (L_SEQ / NCH)    // 64 steps per chunk

typedef short s8v __attribute__((ext_vector_type(8)));
typedef float f32x4 __attribute__((ext_vector_type(4)));

// RNE fp32 -> bf16 split: f ~= hi + lo (each bf16), residual ~2^-17 rel.
__device__ inline void bf16split(float f, unsigned short& hi, unsigned short& lo) {
    unsigned u = __float_as_uint(f);
    unsigned r = (u + 0x7FFFu + ((u >> 16) & 1u)) >> 16;
    hi = (unsigned short)r;
    float fh = __uint_as_float(r << 16);
    float d = f - fh;
    unsigned u2 = __float_as_uint(d);
    lo = (unsigned short)((u2 + 0x7FFFu + ((u2 >> 16) & 1u)) >> 16);
}

// ---------------------------------------------------------------------------
// Elementwise fp32 -> (hi, lo) bf16 arrays. n4 = n/4 thread-groups of float4.
// ---------------------------------------------------------------------------
__global__ __launch_bounds__(256) void cast_split(const float* __restrict__ src,
                                                  unsigned short* __restrict__ hi,
                                                  unsigned short* __restrict__ lo,
                                                  int n4) {
    int idx = blockIdx.x * 256 + threadIdx.x;
    if (idx >= n4) return;
    float4 v = ((const float4*)src)[idx];
    unsigned short h0, h1, h2, h3, l0, l1, l2, l3;
    bf16split(v.x, h0, l0); bf16split(v.y, h1, l1);
    bf16split(v.z, h2, l2); bf16split(v.w, h3, l3);
    ((uint2*)hi)[idx] = make_uint2((unsigned)h0 | ((unsigned)h1 << 16),
                                   (unsigned)h2 | ((unsigned)h3 << 16));
    ((uint2*)lo)[idx] = make_uint2((unsigned)l0 | ((unsigned)l1 << 16),
                                   (unsigned)l2 | ((unsigned)l3 << 16));
}

// ---------------------------------------------------------------------------
// W[K][N] fp32 -> transposed bf16 hi/lo arrays T[N][K]. 32x32 LDS tiles.
// ---------------------------------------------------------------------------
__global__ __launch_bounds__(256) void transpose_split(const float* __restrict__ W,
                                                       unsigned short* __restrict__ Th,
                                                       unsigned short* __restrict__ Tl,
                                                       int K, int N) {
    __shared__ float t[32][33];
    const int k0 = blockIdx.y * 32, n0 = blockIdx.x * 32;
    #pragma unroll
    for (int i = 0; i < 4; ++i) {
        int idx = threadIdx.x + i * 256;
        int r = idx >> 5, c = idx & 31;
        t[r][c] = W[(size_t)(k0 + r) * N + n0 + c];
    }
    __syncthreads();
    #pragma unroll
    for (int i = 0; i < 4; ++i) {
        int idx = threadIdx.x + i * 256;
        int n = idx >> 5, k = idx & 31;
        unsigned short h, l;
        bf16split(t[k][n], h, l);
        Th[(size_t)(n0 + n) * K + k0 + k] = h;
        Tl[(size_t)(n0 + n) * K + k0 + k] = l;
    }
}

// ---------------------------------------------------------------------------
// Split-bf16 MFMA GEMM: C[M][N] = (Ah+Al)[M][K] @ (Bh+Bl)^T[N][K],
// 3 MFMA terms (hi*hi + hi*lo + lo*hi) -> ~fp32 accuracy.
// 128x128 tile, 256 thr (4 waves, each 64x64 as 4x4 16x16x32 frags), BK=32.
// ---------------------------------------------------------------------------
__global__ __launch_bounds__(256) void gemm_bf16s(const unsigned short* __restrict__ Ah,
                                                  const unsigned short* __restrict__ Al,
                                                  const unsigned short* __restrict__ Bh,
                                                  const unsigned short* __restrict__ Bl,
                                                  float* __restrict__ C,
                                                  int M, int N, int K, int ldc) {
    __shared__ unsigned short sAh[128 * 40];  // row stride 40 (=80B, 16B-mult, 2-way-free banks)
    __shared__ unsigned short sAl[128 * 40];
    __shared__ unsigned short sBh[128 * 40];
    __shared__ unsigned short sBl[128 * 40];

    const int tid = threadIdx.x;
    const int bm = blockIdx.y * 128, bn = blockIdx.x * 128;
    const int r0 = tid >> 2;              // 0..63
    const int c0 = (tid & 3) * 8;         // 0,8,16,24

    const int wave = tid >> 6, lane = tid & 63;
    const int wm = (wave >> 1) * 64, wn = (wave & 1) * 64;
    const int lm = lane & 15, lq = lane >> 4;

    f32x4 acc[4][4];
    #pragma unroll
    for (int i = 0; i < 4; ++i)
        #pragma unroll
        for (int j = 0; j < 4; ++j) acc[i][j] = (f32x4){0.f, 0.f, 0.f, 0.f};

    // prefetch tile 0
    s8v pAh0 = *(const s8v*)(Ah + (size_t)(bm + r0) * K + c0);
    s8v pAh1 = *(const s8v*)(Ah + (size_t)(bm + r0 + 64) * K + c0);
    s8v pAl0 = *(const s8v*)(Al + (size_t)(bm + r0) * K + c0);
    s8v pAl1 = *(const s8v*)(Al + (size_t)(bm + r0 + 64) * K + c0);
    s8v pBh0 = *(const s8v*)(Bh + (size_t)(bn + r0) * K + c0);
    s8v pBh1 = *(const s8v*)(Bh + (size_t)(bn + r0 + 64) * K + c0);
    s8v pBl0 = *(const s8v*)(Bl + (size_t)(bn + r0) * K + c0);
    s8v pBl1 = *(const s8v*)(Bl + (size_t)(bn + r0 + 64) * K + c0);

    for (int k0 = 0; k0 < K; k0 += 32) {
        *(s8v*)&sAh[r0 * 40 + c0] = pAh0;  *(s8v*)&sAh[(r0 + 64) * 40 + c0] = pAh1;
        *(s8v*)&sAl[r0 * 40 + c0] = pAl0;  *(s8v*)&sAl[(r0 + 64) * 40 + c0] = pAl1;
        *(s8v*)&sBh[r0 * 40 + c0] = pBh0;  *(s8v*)&sBh[(r0 + 64) * 40 + c0] = pBh1;
        *(s8v*)&sBl[r0 * 40 + c0] = pBl0;  *(s8v*)&sBl[(r0 + 64) * 40 + c0] = pBl1;
        __syncthreads();

        if (k0 + 32 < K) {
            int kk = k0 + 32 + c0;
            pAh0 = *(const s8v*)(Ah + (size_t)(bm + r0) * K + kk);
            pAh1 = *(const s8v*)(Ah + (size_t)(bm + r0 + 64) * K + kk);
            pAl0 = *(const s8v*)(Al + (size_t)(bm + r0) * K + kk);
            pAl1 = *(const s8v*)(Al + (size_t)(bm + r0 + 64) * K + kk);
            pBh0 = *(const s8v*)(Bh + (size_t)(bn + r0) * K + kk);
            pBh1 = *(const s8v*)(Bh + (size_t)(bn + r0 + 64) * K + kk);
            pBl0 = *(const s8v*)(Bl + (size_t)(bn + r0) * K + kk);
            pBl1 = *(const s8v*)(Bl + (size_t)(bn + r0 + 64) * K + kk);
        }

        s8v fah[4], fal[4], fbh[4], fbl[4];
        #pragma unroll
        for (int i = 0; i < 4; ++i) {
            int ar = (wm + i * 16 + lm) * 40 + lq * 8;
            int br = (wn + i * 16 + lm) * 40 + lq * 8;
            fah[i] = *(const s8v*)&sAh[ar];
            fal[i] = *(const s8v*)&sAl[ar];
            fbh[i] = *(const s8v*)&sBh[br];
            fbl[i] = *(const s8v*)&sBl[br];
        }
        #pragma unroll
        for (int mi = 0; mi < 4; ++mi)
            #pragma unroll
            for (int ni = 0; ni < 4; ++ni) {
                acc[mi][ni] = __builtin_amdgcn_mfma_f32_16x16x32_bf16(fah[mi], fbh[ni], acc[mi][ni], 0, 0, 0);
                acc[mi][ni] = __builtin_amdgcn_mfma_f32_16x16x32_bf16(fah[mi], fbl[ni], acc[mi][ni], 0, 0, 0);
                acc[mi][ni] = __builtin_amdgcn_mfma_f32_16x16x32_bf16(fal[mi], fbh[ni], acc[mi][ni], 0, 0, 0);
            }
        __syncthreads();
    }

    // C/D layout: col = lane&15, row = (lane>>4)*4 + reg
    #pragma unroll
    for (int mi = 0; mi < 4; ++mi)
        #pragma unroll
        for (int ni = 0; ni < 4; ++ni) {
            int row = bm + wm + mi * 16 + lq * 4;
            int col = bn + wn + ni * 16 + lm;
            #pragma unroll
            for (int r = 0; r < 4; ++r)
                C[(size_t)(row + r) * ldc + col] = acc[mi][ni][r];
        }
}

// ---------------------------------------------------------------------------
// Depthwise causal conv (k=4) + bias + SiLU.  xr rows [xs | res] width 4096.
// ---------------------------------------------------------------------------
__global__ __launch_bounds__(256) void conv_silu(const float* __restrict__ xr,
                                                 const float* __restrict__ cw,
                                                 const float* __restrict__ cb,
                                                 float* __restrict__ xc) {
    int idx = blockIdx.x * 256 + threadIdx.x;
    int d = idx & (D_INNER - 1);
    int m = idx >> 11;
    int l = m & (L_SEQ - 1);
    float acc = cb[d];
    #pragma unroll
    for (int k = 0; k < 4; ++k) {
        int ll = l - 3 + k;
        if (ll >= 0)
            acc += xr[(size_t)(m - 3 + k) * 4096 + d] * cw[d * 4 + k];
    }
    xc[idx] = acc / (1.f + __expf(-acc));
}

// ---------------------------------------------------------------------------
// x_dbl = xc @ W_x for 4 rows/block; writes dt-part (64), B (16), C (16).
// ---------------------------------------------------------------------------
__global__ __launch_bounds__(256) void xdbl4(const float* __restrict__ xc,
                                             const float* __restrict__ W_x,
                                             float* __restrict__ xdbuf,
                                             float* __restrict__ Bm,
                                             float* __restrict__ Cm) {
    __shared__ float rows[4][D_INNER];  // 32 KB
    __shared__ float xd[4][96];
    const int m0 = blockIdx.x * 4;
    const int t = threadIdx.x;
    #pragma unroll
    for (int i = 0; i < 32; ++i) {
        int idx = t + i * 256;
        int rr = idx >> 11, c = idx & (D_INNER - 1);
        rows[rr][c] = xc[(size_t)(m0 + rr) * D_INNER + c];
    }
    __syncthreads();
    if (t < 192) {
        int g = (t >= 96) ? 1 : 0;
        int c = t - g * 96;
        int ra = g * 2;
        float a0 = 0.f, a1 = 0.f;
        for (int k = 0; k < D_INNER; ++k) {
            float w = W_x[(size_t)k * 96 + c];
            a0 += rows[ra][k] * w;
            a1 += rows[ra + 1][k] * w;
        }
        xd[ra][c] = a0;
        xd[ra + 1][c] = a1;
    }
    __syncthreads();
    #pragma unroll
    for (int i = 0; i < 2; ++i) {
        int idx = t + i * 256;
        if (idx < 384) {
            int rr = idx / 96, cc = idx % 96;
            float v = xd[rr][cc];
            int row = m0 + rr;
            if (cc < 64)      xdbuf[(size_t)row * 64 + cc] = v;
            else if (cc < 80) Bm[(size_t)row * 16 + (cc - 64)] = v;
            else              Cm[(size_t)row * 16 + (cc - 80)] = v;
        }
    }
}

// ---------------------------------------------------------------------------
// delta = softplus(xd @ W_dt + b_dt). Block: 32 rows x 256 d-cols.
// ---------------------------------------------------------------------------
__global__ __launch_bounds__(256) void delta_gemm(const float* __restrict__ xdbuf,
                                                  const float* __restrict__ W_dt,
                                                  const float* __restrict__ b_dt,
                                                  float* __restrict__ delta) {
    __shared__ float sxd[64][36];  // [r][row], stride 36 -> 16B-aligned float4 rows
    const int m0 = blockIdx.x * 32;
    const int d = blockIdx.y * 256 + threadIdx.x;
    #pragma unroll
    for (int i = 0; i < 8; ++i) {
        int idx = threadIdx.x + i * 256;
        int row = idx >> 6, r = idx & 63;
        sxd[r][row] = xdbuf[(size_t)(m0 + row) * 64 + r];
    }
    __syncthreads();
    float acc[32];
    #pragma unroll
    for (int i = 0; i < 32; ++i) acc[i] = 0.f;
    for (int r = 0; r < 64; ++r) {
        float w = W_dt[(size_t)r * D_INNER + d];
        #pragma unroll
        for (int rg = 0; rg < 8; ++rg) {
            float4 v = *(const float4*)&sxd[r][rg * 4];  // broadcast
            acc[rg * 4 + 0] += v.x * w;
            acc[rg * 4 + 1] += v.y * w;
            acc[rg * 4 + 2] += v.z * w;
            acc[rg * 4 + 3] += v.w * w;
        }
    }
    float bd = b_dt[d];
    #pragma unroll
    for (int row = 0; row < 32; ++row) {
        float a = acc[row] + bd;
        float sp = (a > 20.f) ? a : log1pf(__expf(a));
        delta[(size_t)(m0 + row) * D_INNER + d] = sp;
    }
}

// ---------------------------------------------------------------------------
// Scan pass 1: per (b, chunk, d) compute chunk-local final state (h0=0) and
// S = sum(delta) over chunk. Linear recurrence => exact chunk decomposition,
// with chunk decay product = exp(An * S).
// ---------------------------------------------------------------------------
__global__ __launch_bounds__(256) void scan_part1(const float* __restrict__ delta,
                                                  const float* __restrict__ xc,
                                                  const float* __restrict__ Bm,
                                                  const float* __restrict__ A_log,
                                                  float* __restrict__ hlocal,
                                                  float* __restrict__ Ssum) {
    const int t = threadIdx.x;
    const int d = blockIdx.x * 256 + t;
    const int c = blockIdx.y;
    const int b = blockIdx.z;

    float An[16];
    {
        const float4* ap = (const float4*)(A_log + (size_t)d * 16);
        #pragma unroll
        for (int q = 0; q < 4; ++q) {
            float4 v = ap[q];
            An[q * 4 + 0] = -__expf(v.x); An[q * 4 + 1] = -__expf(v.y);
            An[q * 4 + 2] = -__expf(v.z); An[q * 4 + 3] = -__expf(v.w);
        }
    }
    __shared__ float sB[CLEN][16];
    {
        size_t l0 = (size_t)(b * L_SEQ + c * CLEN) * 16;
        #pragma unroll
        for (int i = 0; i < (CLEN * 16) / 256; ++i) {
            int idx = t + i * 256;
            sB[idx >> 4][idx & 15] = Bm[l0 + idx];
        }
    }
    __syncthreads();

    float h[16];
    #pragma unroll
    for (int n = 0; n < 16; ++n) h[n] = 0.f;
    float S = 0.f;

    size_t base = (size_t)(b * L_SEQ + c * CLEN) * D_INNER + d;
    float dv = delta[base], xv = xc[base];
    for (int j = 0; j < CLEN; ++j) {
        float dvn = 0.f, xvn = 0.f;
        if (j < CLEN - 1) {
            dvn = delta[base + (size_t)(j + 1) * D_INNER];
            xvn = xc[base + (size_t)(j + 1) * D_INNER];
        }
        S += dv;
        float dbx = dv * xv;
        #pragma unroll
        for (int n = 0; n < 16; ++n)
            h[n] = __expf(dv * An[n]) * h[n] + dbx * sB[j][n];
        dv = dvn; xv = xvn;
    }

    size_t o = ((size_t)(b * NCH + c) * D_INNER + d) * 16;
    float4* hp = (float4*)(hlocal + o);
    #pragma unroll
    for (int q = 0; q < 4; ++q)
        hp[q] = make_float4(h[q * 4], h[q * 4 + 1], h[q * 4 + 2], h[q * 4 + 3]);
    Ssum[(size_t)(b * NCH + c) * D_INNER + d] = S;
}

// ---------------------------------------------------------------------------
// Combine: sequential over 32 chunks per (b,d,n); writes each chunk's h0.
// ---------------------------------------------------------------------------
__global__ __launch_bounds__(256) void scan_combine(const float* __restrict__ hlocal,
                                                    const float* __restrict__ Ssum,
                                                    const float* __restrict__ A_log,
                                                    float* __restrict__ h0buf) {
    int gid = blockIdx.x * 256 + threadIdx.x;
    int n = gid & 15;
    int d = (gid >> 4) & (D_INNER - 1);
    int b = gid >> 15;
    float An = -__expf(A_log[(size_t)d * 16 + n]);
    float H = 0.f;
    for (int c = 0; c < NCH; ++c) {
        size_t sc = (size_t)(b * NCH + c) * D_INNER + d;
        float S = Ssum[sc];
        size_t o = sc * 16 + n;
        float hl = hlocal[o];
        h0buf[o] = H;
        H = __expf(An * S) * H + hl;
    }
}

// ---------------------------------------------------------------------------
// Scan pass 2: replay chunks from correct h0; y = sum_n h*C; fuse +xc*D and
// *silu(res); write y as bf16 hi/lo (A-operand of the output GEMM).
// ---------------------------------------------------------------------------
__global__ __launch_bounds__(256) void scan_part2(const float* __restrict__ delta,
                                                  const float* __restrict__ xc,
                                                  const float* __restrict__ Bm,
                                                  const float* __restrict__ Cm,
                                                  const float* __restrict__ h0buf,
                                                  const float* __restrict__ A_log,
                                                  const float* __restrict__ Dp,
                                                  const float* __restrict__ xr,
                                                  unsigned short* __restrict__ yh,
                                                  unsigned short* __restrict__ yl) {
    const int t = threadIdx.x;
    const int d = blockIdx.x * 256 + t;
    const int c = blockIdx.y;
    const int b = blockIdx.z;

    float An[16];
    {
        const float4* ap = (const float4*)(A_log + (size_t)d * 16);
        #pragma unroll
        for (int q = 0; q < 4; ++q) {
            float4 v = ap[q];
            An[q * 4 + 0] = -__expf(v.x); An[q * 4 + 1] = -__expf(v.y);
            An[q * 4 + 2] = -__expf(v.z); An[q * 4 + 3] = -__expf(v.w);
        }
    }
    __shared__ float sB[CLEN][16];
    __shared__ float sC[CLEN][16];
    {
        size_t l0 = (size_t)(b * L_SEQ + c * CLEN) * 16;
        #pragma unroll
        for (int i = 0; i < (CLEN * 16) / 256; ++i) {
            int idx = t + i * 256;
            sB[idx >> 4][idx & 15] = Bm[l0 + idx];
            sC[idx >> 4][idx & 15] = Cm[l0 + idx];
        }
    }
    __syncthreads();

    float h[16];
    {
        size_t o = ((size_t)(b * NCH + c) * D_INNER + d) * 16;
        const float4* hp = (const float4*)(h0buf + o);
        #pragma unroll
        for (int q = 0; q < 4; ++q) {
            float4 v = hp[q];
            h[q * 4 + 0] = v.x; h[q * 4 + 1] = v.y;
            h[q * 4 + 2] = v.z; h[q * 4 + 3] = v.w;
        }
    }
    const float Dv = Dp[d];

    size_t base  = (size_t)(b * L_SEQ + c * CLEN) * D_INNER + d;
    size_t rbase = (size_t)(b * L_SEQ + c * CLEN) * 4096 + 2048 + d;
    float dv = delta[base], xv = xc[base], rv = xr[rbase];
    for (int j = 0; j < CLEN; ++j) {
        float dvn = 0.f, xvn = 0.f, rvn = 0.f;
        if (j < CLEN - 1) {
            dvn = delta[base + (size_t)(j + 1) * D_INNER];
            xvn = xc[base + (size_t)(j + 1) * D_INNER];
            rvn = xr[rbase + (size_t)(j + 1) * 4096];
        }
        float dbx = dv * xv;
        float y = 0.f;
        #pragma unroll
        for (int n = 0; n < 16; ++n) {
            h[n] = __expf(dv * An[n]) * h[n] + dbx * sB[j][n];
            y += h[n] * sC[j][n];
        }
        float sres = rv / (1.f + __expf(-rv));
        float yv = (y + xv * Dv) * sres;
        unsigned short hh, ll;
        bf16split(yv, hh, ll);
        size_t row = (size_t)(b * L_SEQ + c * CLEN + j) * D_INNER + d;
        yh[row] = hh;
        yl[row] = ll;
        dv = dvn; xv = xvn; rv = rvn;
    }
}

extern "C" void kernel_launch(void* const* d_in, const int* in_sizes, int n_in,
                              void* d_out, int out_size, void* d_ws, size_t ws_size,
                              hipStream_t stream) {
    const float* x      = (const float*)d_in[0];
    const float* W_in   = (const float*)d_in[1];
    const float* conv_w = (const float*)d_in[2];
    const float* conv_b = (const float*)d_in[3];
    const float* W_x    = (const float*)d_in[4];
    const float* W_dt   = (const float*)d_in[5];
    const float* b_dt   = (const float*)d_in[6];
    const float* A_log  = (const float*)d_in[7];
    const float* D_par  = (const float*)d_in[8];
    const float* W_out  = (const float*)d_in[9];
    float* out = (float*)d_out;

    char* wsb = (char*)d_ws;
    float* xr    = (float*)(wsb + 0);                     //  67,108,864 B
    float* xc    = (float*)(wsb + 67108864);              //  33,554,432 B
    float* delta = (float*)(wsb + 100663296);             //  33,554,432 B
    // bf16 staging for K1 aliased over delta (dead until delta_gemm runs):
    unsigned short* xh  = (unsigned short*)(wsb + 100663296);  // 8,388,608 B
    unsigned short* xl  = (unsigned short*)(wsb + 109051904);
    unsigned short* Wht = (unsigned short*)(wsb + 117440512);
    unsigned short* Wlt = (unsigned short*)(wsb + 125829120);
    float* Bbuf  = (float*)(wsb + 134217728);             //     262,144 B
    float* Cbuf  = (float*)(wsb + 134479872);             //     262,144 B
    float* xdbuf = (float*)(wsb + 134742016);             //   1,048,576 B
    float* Ssum  = (float*)(wsb + 135790592);             //     524,288 B
    float* hloc  = (float*)(wsb + 136314880);             //   8,388,608 B
    float* h0buf = (float*)(wsb + 144703488);             //   8,388,608 B
    unsigned short* yh  = (unsigned short*)(wsb + 153092096);  // 16,777,216 B
    unsigned short* yl  = (unsigned short*)(wsb + 169869312);  // 16,777,216 B
    unsigned short* Woh = (unsigned short*)(wsb + 186646528);  //  4,194,304 B
    unsigned short* Wol = (unsigned short*)(wsb + 190840832);  //  4,194,304 B

    dim3 blk(256);

    // 1. cast x -> bf16 hi/lo (4096x1024)
    cast_split<<<dim3((MM * D_MODEL / 4) / 256), blk, 0, stream>>>(x, xh, xl, MM * D_MODEL / 4);
    // 2. W_in [1024][4096] -> transposed hi/lo [4096][1024]
    transpose_split<<<dim3(4096 / 32, 1024 / 32), blk, 0, stream>>>(W_in, Wht, Wlt, D_MODEL, 2 * D_INNER);
    // 3. K1: xr = x @ W_in   (M=4096, N=4096, K=1024) via split-bf16 MFMA
    gemm_bf16s<<<dim3(32, 32), blk, 0, stream>>>(xh, xl, Wht, Wlt, xr, MM, 2 * D_INNER, D_MODEL, 2 * D_INNER);
    // 4. conv + SiLU
    conv_silu<<<dim3((size_t)MM * D_INNER / 256), blk, 0, stream>>>(xr, conv_w, conv_b, xc);
    // 5. x_dbl (dt-part, B, C)
    xdbl4<<<dim3(MM / 4), blk, 0, stream>>>(xc, W_x, xdbuf, Bbuf, Cbuf);
    // 6. delta (overwrites the bf16 staging alias — K1 is done with it)
    delta_gemm<<<dim3(MM / 32, D_INNER / 256), blk, 0, stream>>>(xdbuf, W_dt, b_dt, delta);
    // 7. scan pass 1
    scan_part1<<<dim3(D_INNER / 256, NCH, B_SZ), blk, 0, stream>>>(delta, xc, Bbuf, A_log, hloc, Ssum);
    // 8. combine
    scan_combine<<<dim3(B_SZ * D_INNER * 16 / 256), blk, 0, stream>>>(hloc, Ssum, A_log, h0buf);
    // 9. W_out [2048][1024] -> transposed hi/lo [1024][2048]
    transpose_split<<<dim3(1024 / 32, 2048 / 32), blk, 0, stream>>>(W_out, Woh, Wol, D_INNER, D_MODEL);
    // 10. scan pass 2 (+gating, writes y as bf16 hi/lo)
    scan_part2<<<dim3(D_INNER / 256, NCH, B_SZ), blk, 0, stream>>>(delta, xc, Bbuf, Cbuf, h0buf, A_log, D_par, xr, yh, yl);
    // 11. K5: out = y @ W_out  (M=4096, N=1024, K=2048)
    gemm_bf16s<<<dim3(8, 32), blk, 0, stream>>>(yh, yl, Woh, Wol, out, MM, D_MODEL, D_INNER, D_MODEL);
}

// Round 4
// 375.202 us; speedup vs baseline: 7.3681x; 1.5575x over previous
//
#include <hip/hip_runtime.h>
#include <math.h>

#define B_SZ    2
#define L_SEQ   2048
#define D_MODEL 1024
#define D_INNER 2048
#define D_STATE 16
#define DT_RANK 64
#define MM      (B_SZ * L_SEQ)   // 4096 rows
#define NCH     32               // scan chunks
#define CLEN    (L_SEQ / NCH)    // 64 steps per chunk

typedef _Float16 h8v __attribute__((ext_vector_type(8)));
typedef _Float16 h4v __attribute__((ext_vector_type(4)));
typedef float f32x4 __attribute__((ext_vector_type(4)));

// ---------------------------------------------------------------------------
// fp32 -> fp16 elementwise cast. n4 = n/4 float4 groups.
// ---------------------------------------------------------------------------
__global__ __launch_bounds__(256) void cast_f16(const float* __restrict__ src,
                                                _Float16* __restrict__ dst, int n4) {
    int idx = blockIdx.x * 256 + threadIdx.x;
    if (idx >= n4) return;
    float4 v = ((const float4*)src)[idx];
    h4v h = {(_Float16)v.x, (_Float16)v.y, (_Float16)v.z, (_Float16)v.w};
    *(h4v*)(dst + (size_t)idx * 4) = h;
}

// ---------------------------------------------------------------------------
// W[K][N] fp32 -> transposed fp16 T[N][K]. 32x32 LDS tiles; K,N mult of 32.
// ---------------------------------------------------------------------------
__global__ __launch_bounds__(256) void transpose_f16(const float* __restrict__ W,
                                                     _Float16* __restrict__ T,
                                                     int K, int N) {
    __shared__ float t[32][33];
    const int k0 = blockIdx.y * 32, n0 = blockIdx.x * 32;
    #pragma unroll
    for (int i = 0; i < 4; ++i) {
        int idx = threadIdx.x + i * 256;
        int r = idx >> 5, c = idx & 31;
        t[r][c] = W[(size_t)(k0 + r) * N + n0 + c];
    }
    __syncthreads();
    #pragma unroll
    for (int i = 0; i < 4; ++i) {
        int idx = threadIdx.x + i * 256;
        int n = idx >> 5, k = idx & 31;
        T[(size_t)(n0 + n) * K + k0 + k] = (_Float16)t[k][n];
    }
}

// ---------------------------------------------------------------------------
// fp16 MFMA GEMM: C[M][N] = A[M][K] @ Bt[N][K]^T, fp32 accumulate/output.
// 128x128 tile, 256 thr (4 waves, each 64x64 as 4x4 16x16x32 frags), BK=32.
// EPI 0: plain store. EPI 1: softplus(acc + bias[col]) (delta epilogue).
// ---------------------------------------------------------------------------
template<int EPI>
__global__ __launch_bounds__(256) void gemm_f16(const _Float16* __restrict__ A,
                                                const _Float16* __restrict__ Bt,
                                                const float* __restrict__ bias,
                                                float* __restrict__ C,
                                                int M, int N, int K, int ldc) {
    __shared__ _Float16 sA[128 * 40];  // row stride 40 halfs = 80 B (bank-clean, 16B-mult)
    __shared__ _Float16 sB[128 * 40];

    const int tid = threadIdx.x;
    const int bm = blockIdx.y * 128, bn = blockIdx.x * 128;
    const int r0 = tid >> 2;              // 0..63
    const int c0 = (tid & 3) * 8;         // 0,8,16,24

    const int wave = tid >> 6, lane = tid & 63;
    const int wm = (wave >> 1) * 64, wn = (wave & 1) * 64;
    const int lm = lane & 15, lq = lane >> 4;

    f32x4 acc[4][4];
    #pragma unroll
    for (int i = 0; i < 4; ++i)
        #pragma unroll
        for (int j = 0; j < 4; ++j) acc[i][j] = (f32x4){0.f, 0.f, 0.f, 0.f};

    h8v pA0 = *(const h8v*)(A + (size_t)(bm + r0) * K + c0);
    h8v pA1 = *(const h8v*)(A + (size_t)(bm + r0 + 64) * K + c0);
    h8v pB0 = *(const h8v*)(Bt + (size_t)(bn + r0) * K + c0);
    h8v pB1 = *(const h8v*)(Bt + (size_t)(bn + r0 + 64) * K + c0);

    for (int k0 = 0; k0 < K; k0 += 32) {
        *(h8v*)&sA[r0 * 40 + c0] = pA0;  *(h8v*)&sA[(r0 + 64) * 40 + c0] = pA1;
        *(h8v*)&sB[r0 * 40 + c0] = pB0;  *(h8v*)&sB[(r0 + 64) * 40 + c0] = pB1;
        __syncthreads();

        if (k0 + 32 < K) {
            int kk = k0 + 32 + c0;
            pA0 = *(const h8v*)(A + (size_t)(bm + r0) * K + kk);
            pA1 = *(const h8v*)(A + (size_t)(bm + r0 + 64) * K + kk);
            pB0 = *(const h8v*)(Bt + (size_t)(bn + r0) * K + kk);
            pB1 = *(const h8v*)(Bt + (size_t)(bn + r0 + 64) * K + kk);
        }

        h8v fa[4], fb[4];
        #pragma unroll
        for (int i = 0; i < 4; ++i) {
            fa[i] = *(const h8v*)&sA[(wm + i * 16 + lm) * 40 + lq * 8];
            fb[i] = *(const h8v*)&sB[(wn + i * 16 + lm) * 40 + lq * 8];
        }
        #pragma unroll
        for (int mi = 0; mi < 4; ++mi)
            #pragma unroll
            for (int ni = 0; ni < 4; ++ni)
                acc[mi][ni] = __builtin_amdgcn_mfma_f32_16x16x32_f16(fa[mi], fb[ni], acc[mi][ni], 0, 0, 0);
        __syncthreads();
    }

    // C/D layout: col = lane&15, row = (lane>>4)*4 + reg
    #pragma unroll
    for (int mi = 0; mi < 4; ++mi)
        #pragma unroll
        for (int ni = 0; ni < 4; ++ni) {
            int row = bm + wm + mi * 16 + lq * 4;
            int col = bn + wn + ni * 16 + lm;
            #pragma unroll
            for (int r = 0; r < 4; ++r) {
                float v = acc[mi][ni][r];
                if (EPI == 1) {
                    float a = v + bias[col];
                    v = (a > 20.f) ? a : log1pf(__expf(a));
                }
                C[(size_t)(row + r) * ldc + col] = v;
            }
        }
}

// ---------------------------------------------------------------------------
// Skinny fp16 MFMA GEMM for x_dbl: xd[4096][96] = xch[4096][2048] @ WxT[96][2048]^T.
// Block = 64 rows; 4 waves, each 16 rows x 96 cols (6 n-frags). BK=32.
// Epilogue scatters: cols 0..63 -> xdh (fp16), 64..79 -> Bm, 80..95 -> Cm.
// ---------------------------------------------------------------------------
__global__ __launch_bounds__(256) void gemm_xd(const _Float16* __restrict__ xch,
                                               const _Float16* __restrict__ WxT,
                                               _Float16* __restrict__ xdh,
                                               float* __restrict__ Bm,
                                               float* __restrict__ Cm) {
    __shared__ _Float16 sA[64 * 40];
    __shared__ _Float16 sB[96 * 40];
    const int tid = threadIdx.x;
    const int m0 = blockIdx.x * 64;
    const int wave = tid >> 6, lane = tid & 63;
    const int lm = lane & 15, lq = lane >> 4;
    const int r0 = tid >> 2, c0 = (tid & 3) * 8;
    const int br1 = 64 + (tid >> 2) / 2;            // unused helper removed below
    (void)br1;

    f32x4 acc[6];
    #pragma unroll
    for (int i = 0; i < 6; ++i) acc[i] = (f32x4){0.f, 0.f, 0.f, 0.f};

    // B staging: 96 rows x 4 chunks of 8 halfs = 384 chunks; thread t does
    // chunk t and (t<128) chunk t+256.
    const int br0 = tid >> 2, bc0 = (tid & 3) * 8;
    const int bidx1 = tid + 256;
    const int br2 = bidx1 >> 2, bc2 = (bidx1 & 3) * 8;

    h8v pA = *(const h8v*)(xch + (size_t)(m0 + r0) * D_INNER + c0);
    h8v pB0 = *(const h8v*)(WxT + (size_t)br0 * D_INNER + bc0);
    h8v pB1 = (tid < 128) ? *(const h8v*)(WxT + (size_t)br2 * D_INNER + bc2) : (h8v)0;

    for (int k0 = 0; k0 < D_INNER; k0 += 32) {
        *(h8v*)&sA[r0 * 40 + c0] = pA;
        *(h8v*)&sB[br0 * 40 + bc0] = pB0;
        if (tid < 128) *(h8v*)&sB[br2 * 40 + bc2] = pB1;
        __syncthreads();

        if (k0 + 32 < D_INNER) {
            pA = *(const h8v*)(xch + (size_t)(m0 + r0) * D_INNER + k0 + 32 + c0);
            pB0 = *(const h8v*)(WxT + (size_t)br0 * D_INNER + k0 + 32 + bc0);
            if (tid < 128) pB1 = *(const h8v*)(WxT + (size_t)br2 * D_INNER + k0 + 32 + bc2);
        }

        h8v fa = *(const h8v*)&sA[(wave * 16 + lm) * 40 + lq * 8];
        #pragma unroll
        for (int nf = 0; nf < 6; ++nf) {
            h8v fb = *(const h8v*)&sB[(nf * 16 + lm) * 40 + lq * 8];
            acc[nf] = __builtin_amdgcn_mfma_f32_16x16x32_f16(fa, fb, acc[nf], 0, 0, 0);
        }
        __syncthreads();
    }

    #pragma unroll
    for (int nf = 0; nf < 6; ++nf) {
        int col = nf * 16 + lm;
        #pragma unroll
        for (int r = 0; r < 4; ++r) {
            int row = m0 + wave * 16 + lq * 4 + r;
            float v = acc[nf][r];
            if (col < 64)      xdh[(size_t)row * 64 + col] = (_Float16)v;
            else if (col < 80) Bm[(size_t)row * 16 + (col - 64)] = v;
            else               Cm[(size_t)row * 16 + (col - 80)] = v;
        }
    }
}

// ---------------------------------------------------------------------------
// Depthwise causal conv (k=4) + bias + SiLU; emits fp32 xc and fp16 copy.
// ---------------------------------------------------------------------------
__global__ __launch_bounds__(256) void conv_silu(const float* __restrict__ xr,
                                                 const float* __restrict__ cw,
                                                 const float* __restrict__ cb,
                                                 float* __restrict__ xc,
                                                 _Float16* __restrict__ xch) {
    int idx = blockIdx.x * 256 + threadIdx.x;
    int d = idx & (D_INNER - 1);
    int m = idx >> 11;
    int l = m & (L_SEQ - 1);
    float acc = cb[d];
    #pragma unroll
    for (int k = 0; k < 4; ++k) {
        int ll = l - 3 + k;
        if (ll >= 0)
            acc += xr[(size_t)(m - 3 + k) * 4096 + d] * cw[d * 4 + k];
    }
    float s = acc / (1.f + __expf(-acc));
    xc[idx] = s;
    xch[idx] = (_Float16)s;
}

// ---------------------------------------------------------------------------
// Scan pass 1: per (b, chunk, d) chunk-local final state (h0=0) + S=sum(delta).
// ---------------------------------------------------------------------------
__global__ __launch_bounds__(256) void scan_part1(const float* __restrict__ delta,
                                                  const float* __restrict__ xc,
                                                  const float* __restrict__ Bm,
                                                  const float* __restrict__ A_log,
                                                  float* __restrict__ hlocal,
                                                  float* __restrict__ Ssum) {
    const int t = threadIdx.x;
    const int d = blockIdx.x * 256 + t;
    const int c = blockIdx.y;
    const int b = blockIdx.z;

    float An[16];
    {
        const float4* ap = (const float4*)(A_log + (size_t)d * 16);
        #pragma unroll
        for (int q = 0; q < 4; ++q) {
            float4 v = ap[q];
            An[q * 4 + 0] = -__expf(v.x); An[q * 4 + 1] = -__expf(v.y);
            An[q * 4 + 2] = -__expf(v.z); An[q * 4 + 3] = -__expf(v.w);
        }
    }
    __shared__ float sB[CLEN][16];
    {
        size_t l0 = (size_t)(b * L_SEQ + c * CLEN) * 16;
        #pragma unroll
        for (int i = 0; i < (CLEN * 16) / 256; ++i) {
            int idx = t + i * 256;
            sB[idx >> 4][idx & 15] = Bm[l0 + idx];
        }
    }
    __syncthreads();

    float h[16];
    #pragma unroll
    for (int n = 0; n < 16; ++n) h[n] = 0.f;
    float S = 0.f;

    size_t base = (size_t)(b * L_SEQ + c * CLEN) * D_INNER + d;
    float dv = delta[base], xv = xc[base];
    for (int j = 0; j < CLEN; ++j) {
        float dvn = 0.f, xvn = 0.f;
        if (j < CLEN - 1) {
            dvn = delta[base + (size_t)(j + 1) * D_INNER];
            xvn = xc[base + (size_t)(j + 1) * D_INNER];
        }
        S += dv;
        float dbx = dv * xv;
        #pragma unroll
        for (int n = 0; n < 16; ++n)
            h[n] = __expf(dv * An[n]) * h[n] + dbx * sB[j][n];
        dv = dvn; xv = xvn;
    }

    size_t o = ((size_t)(b * NCH + c) * D_INNER + d) * 16;
    float4* hp = (float4*)(hlocal + o);
    #pragma unroll
    for (int q = 0; q < 4; ++q)
        hp[q] = make_float4(h[q * 4], h[q * 4 + 1], h[q * 4 + 2], h[q * 4 + 3]);
    Ssum[(size_t)(b * NCH + c) * D_INNER + d] = S;
}

// ---------------------------------------------------------------------------
// Combine: sequential over 32 chunks per (b,d,n); writes each chunk's h0.
// ---------------------------------------------------------------------------
__global__ __launch_bounds__(256) void scan_combine(const float* __restrict__ hlocal,
                                                    const float* __restrict__ Ssum,
                                                    const float* __restrict__ A_log,
                                                    float* __restrict__ h0buf) {
    int gid = blockIdx.x * 256 + threadIdx.x;
    int n = gid & 15;
    int d = (gid >> 4) & (D_INNER - 1);
    int b = gid >> 15;
    float An = -__expf(A_log[(size_t)d * 16 + n]);
    float H = 0.f;
    for (int c = 0; c < NCH; ++c) {
        size_t sc = (size_t)(b * NCH + c) * D_INNER + d;
        float S = Ssum[sc];
        size_t o = sc * 16 + n;
        float hl = hlocal[o];
        h0buf[o] = H;
        H = __expf(An * S) * H + hl;
    }
}

// ---------------------------------------------------------------------------
// Scan pass 2: replay from h0; y = sum_n h*C; fuse +xc*D and *silu(res);
// write y as fp16 (A-operand of the output GEMM).
// ---------------------------------------------------------------------------
__global__ __launch_bounds__(256) void scan_part2(const float* __restrict__ delta,
                                                  const float* __restrict__ xc,
                                                  const float* __restrict__ Bm,
                                                  const float* __restrict__ Cm,
                                                  const float* __restrict__ h0buf,
                                                  const float* __restrict__ A_log,
                                                  const float* __restrict__ Dp,
                                                  const float* __restrict__ xr,
                                                  _Float16* __restrict__ yhalf) {
    const int t = threadIdx.x;
    const int d = blockIdx.x * 256 + t;
    const int c = blockIdx.y;
    const int b = blockIdx.z;

    float An[16];
    {
        const float4* ap = (const float4*)(A_log + (size_t)d * 16);
        #pragma unroll
        for (int q = 0; q < 4; ++q) {
            float4 v = ap[q];
            An[q * 4 + 0] = -__expf(v.x); An[q * 4 + 1] = -__expf(v.y);
            An[q * 4 + 2] = -__expf(v.z); An[q * 4 + 3] = -__expf(v.w);
        }
    }
    __shared__ float sB[CLEN][16];
    __shared__ float sC[CLEN][16];
    {
        size_t l0 = (size_t)(b * L_SEQ + c * CLEN) * 16;
        #pragma unroll
        for (int i = 0; i < (CLEN * 16) / 256; ++i) {
            int idx = t + i * 256;
            sB[idx >> 4][idx & 15] = Bm[l0 + idx];
            sC[idx >> 4][idx & 15] = Cm[l0 + idx];
        }
    }
    __syncthreads();

    float h[16];
    {
        size_t o = ((size_t)(b * NCH + c) * D_INNER + d) * 16;
        const float4* hp = (const float4*)(h0buf + o);
        #pragma unroll
        for (int q = 0; q < 4; ++q) {
            float4 v = hp[q];
            h[q * 4 + 0] = v.x; h[q * 4 + 1] = v.y;
            h[q * 4 + 2] = v.z; h[q * 4 + 3] = v.w;
        }
    }
    const float Dv = Dp[d];

    size_t base  = (size_t)(b * L_SEQ + c * CLEN) * D_INNER + d;
    size_t rbase = (size_t)(b * L_SEQ + c * CLEN) * 4096 + 2048 + d;
    float dv = delta[base], xv = xc[base], rv = xr[rbase];
    for (int j = 0; j < CLEN; ++j) {
        float dvn = 0.f, xvn = 0.f, rvn = 0.f;
        if (j < CLEN - 1) {
            dvn = delta[base + (size_t)(j + 1) * D_INNER];
            xvn = xc[base + (size_t)(j + 1) * D_INNER];
            rvn = xr[rbase + (size_t)(j + 1) * 4096];
        }
        float dbx = dv * xv;
        float y = 0.f;
        #pragma unroll
        for (int n = 0; n < 16; ++n) {
            h[n] = __expf(dv * An[n]) * h[n] + dbx * sB[j][n];
            y += h[n] * sC[j][n];
        }
        float sres = rv / (1.f + __expf(-rv));
        float yv = (y + xv * Dv) * sres;
        size_t row = (size_t)(b * L_SEQ + c * CLEN + j) * D_INNER + d;
        yhalf[row] = (_Float16)yv;
        dv = dvn; xv = xvn; rv = rvn;
    }
}

extern "C" void kernel_launch(void* const* d_in, const int* in_sizes, int n_in,
                              void* d_out, int out_size, void* d_ws, size_t ws_size,
                              hipStream_t stream) {
    const float* x      = (const float*)d_in[0];
    const float* W_in   = (const float*)d_in[1];
    const float* conv_w = (const float*)d_in[2];
    const float* conv_b = (const float*)d_in[3];
    const float* W_x    = (const float*)d_in[4];
    const float* W_dt   = (const float*)d_in[5];
    const float* b_dt   = (const float*)d_in[6];
    const float* A_log  = (const float*)d_in[7];
    const float* D_par  = (const float*)d_in[8];
    const float* W_out  = (const float*)d_in[9];
    float* out = (float*)d_out;

    char* wsb = (char*)d_ws;
    float*     xr    = (float*)(wsb + 0);               //  67,108,864 B
    float*     xc    = (float*)(wsb + 67108864);        //  33,554,432 B
    float*     delta = (float*)(wsb + 100663296);       //  33,554,432 B
    _Float16*  xf16  = (_Float16*)(wsb + 134217728);    //   8,388,608 B (dead after K1)
    _Float16*  WinT  = (_Float16*)(wsb + 142606336);    //   8,388,608 B (dead after K1)
    _Float16*  yhalf = (_Float16*)(wsb + 134217728);    //  16,777,216 B (aliases xf16+WinT)
    _Float16*  xch   = (_Float16*)(wsb + 150994944);    //  16,777,216 B
    _Float16*  WxT   = (_Float16*)(wsb + 167772160);    //     393,216 B
    _Float16*  xdh   = (_Float16*)(wsb + 168165376);    //     524,288 B
    _Float16*  WdtT  = (_Float16*)(wsb + 168689664);    //     262,144 B
    float*     Bbuf  = (float*)(wsb + 168951808);       //     262,144 B
    float*     Cbuf  = (float*)(wsb + 169213952);       //     262,144 B
    float*     Ssum  = (float*)(wsb + 169476096);       //     524,288 B
    float*     hloc  = (float*)(wsb + 170000384);       //   8,388,608 B
    float*     h0buf = (float*)(wsb + 178388992);       //   8,388,608 B
    _Float16*  WoutT = (_Float16*)(wsb + 186777600);    //   4,194,304 B
    // end: 190,971,904 B (within footprint proven in R3)

    dim3 blk(256);

    // 1. x -> fp16
    cast_f16<<<dim3((MM * D_MODEL / 4) / 256), blk, 0, stream>>>(x, xf16, MM * D_MODEL / 4);
    // 2. W_in [1024][4096] -> fp16 transposed [4096][1024]
    transpose_f16<<<dim3(4096 / 32, 1024 / 32), blk, 0, stream>>>(W_in, WinT, D_MODEL, 2 * D_INNER);
    // 3. K1: xr = x @ W_in  (M=4096, N=4096, K=1024)
    gemm_f16<0><<<dim3(32, 32), blk, 0, stream>>>(xf16, WinT, nullptr, xr, MM, 2 * D_INNER, D_MODEL, 2 * D_INNER);
    // 4. conv + SiLU (fp32 + fp16 outputs)
    conv_silu<<<dim3((size_t)MM * D_INNER / 256), blk, 0, stream>>>(xr, conv_w, conv_b, xc, xch);
    // 5. W_x [2048][96] -> fp16 transposed [96][2048]
    transpose_f16<<<dim3(96 / 32, 2048 / 32), blk, 0, stream>>>(W_x, WxT, D_INNER, 96);
    // 6. xd = xc @ W_x (skinny): xdh fp16 + B, C fp32
    gemm_xd<<<dim3(MM / 64), blk, 0, stream>>>(xch, WxT, xdh, Bbuf, Cbuf);
    // 7. W_dt [64][2048] -> fp16 transposed [2048][64]
    transpose_f16<<<dim3(2048 / 32, 64 / 32), blk, 0, stream>>>(W_dt, WdtT, DT_RANK, D_INNER);
    // 8. delta = softplus(xd @ W_dt + b_dt)  (M=4096, N=2048, K=64)
    gemm_f16<1><<<dim3(16, 32), blk, 0, stream>>>(xdh, WdtT, b_dt, delta, MM, D_INNER, DT_RANK, D_INNER);
    // 9. scan pass 1
    scan_part1<<<dim3(D_INNER / 256, NCH, B_SZ), blk, 0, stream>>>(delta, xc, Bbuf, A_log, hloc, Ssum);
    // 10. combine
    scan_combine<<<dim3(B_SZ * D_INNER * 16 / 256), blk, 0, stream>>>(hloc, Ssum, A_log, h0buf);
    // 11. W_out [2048][1024] -> fp16 transposed [1024][2048]
    transpose_f16<<<dim3(1024 / 32, 2048 / 32), blk, 0, stream>>>(W_out, WoutT, D_INNER, D_MODEL);
    // 12. scan pass 2 (+gating) -> yhalf fp16 (aliases dead xf16/WinT)
    scan_part2<<<dim3(D_INNER / 256, NCH, B_SZ), blk, 0, stream>>>(delta, xc, Bbuf, Cbuf, h0buf, A_log, D_par, xr, yhalf);
    // 13. K5: out = y @ W_out  (M=4096, N=1024, K=2048)
    gemm_f16<0><<<dim3(8, 32), blk, 0, stream>>>(yhalf, WoutT, nullptr, out, MM, D_MODEL, D_INNER, D_MODEL);
}

// Round 5
// 364.158 us; speedup vs baseline: 7.5915x; 1.0303x over previous
//
#include <hip/hip_runtime.h>
#include <math.h>

#define B_SZ    2
#define L_SEQ   2048
#define D_MODEL 1024
#define D_INNER 2048
#define D_STATE 16
#define DT_RANK 64
#define MM      (B_SZ * L_SEQ)   // 4096 rows
#define NCH     64               // scan chunks
#define CLEN    (L_SEQ / NCH)    // 32 steps per chunk
#define PFD     8                // scan prefetch depth

typedef _Float16 h8v __attribute__((ext_vector_type(8)));
typedef _Float16 h4v __attribute__((ext_vector_type(4)));
typedef float f32x4 __attribute__((ext_vector_type(4)));

// ---------------------------------------------------------------------------
// fp32 -> fp16 elementwise cast. n4 = n/4 float4 groups.
// ---------------------------------------------------------------------------
__global__ __launch_bounds__(256) void cast_f16(const float* __restrict__ src,
                                                _Float16* __restrict__ dst, int n4) {
    int idx = blockIdx.x * 256 + threadIdx.x;
    if (idx >= n4) return;
    float4 v = ((const float4*)src)[idx];
    h4v h = {(_Float16)v.x, (_Float16)v.y, (_Float16)v.z, (_Float16)v.w};
    *(h4v*)(dst + (size_t)idx * 4) = h;
}

// ---------------------------------------------------------------------------
// W[K][N] fp32 -> transposed fp16 T[N][K]. 32x32 LDS tiles; K,N mult of 32.
// ---------------------------------------------------------------------------
__global__ __launch_bounds__(256) void transpose_f16(const float* __restrict__ W,
                                                     _Float16* __restrict__ T,
                                                     int K, int N) {
    __shared__ float t[32][33];
    const int k0 = blockIdx.y * 32, n0 = blockIdx.x * 32;
    #pragma unroll
    for (int i = 0; i < 4; ++i) {
        int idx = threadIdx.x + i * 256;
        int r = idx >> 5, c = idx & 31;
        t[r][c] = W[(size_t)(k0 + r) * N + n0 + c];
    }
    __syncthreads();
    #pragma unroll
    for (int i = 0; i < 4; ++i) {
        int idx = threadIdx.x + i * 256;
        int n = idx >> 5, k = idx & 31;
        T[(size_t)(n0 + n) * K + k0 + k] = (_Float16)t[k][n];
    }
}

// ---------------------------------------------------------------------------
// fp16 MFMA GEMM: C[M][N] = A[M][K] @ Bt[N][K]^T, fp32 accumulate.
// 128x128 tile, 256 thr (4 waves, each 64x64 as 4x4 16x16x32 frags), BK=32.
// LDS: row stride 32 halfs + XOR chunk swizzle p = c ^ ((row>>1)&3):
// uniform 2-way on both staging writes and frag reads (2-way is free, m136).
// EPI 0: plain store to C (ld=ldc).
// EPI 1: softplus(acc + bias[col]) -> C  (delta epilogue).
// EPI 2: col<2048 -> C fp32 (ld 2048); col>=2048 -> silu -> H fp16 (ld 2048).
// ---------------------------------------------------------------------------
template<int EPI>
__global__ __launch_bounds__(256) void gemm_f16(const _Float16* __restrict__ A,
                                                const _Float16* __restrict__ Bt,
                                                const float* __restrict__ bias,
                                                float* __restrict__ C,
                                                _Float16* __restrict__ H,
                                                int M, int N, int K, int ldc) {
    __shared__ _Float16 sA[128 * 32];
    __shared__ _Float16 sB[128 * 32];

    const int tid = threadIdx.x;
    const int bm = blockIdx.y * 128, bn = blockIdx.x * 128;

    // staging: thread -> row wr (and wr+64), chunk wc (8 halfs)
    const int wr = tid >> 2;
    const int wc = tid & 3;
    const int c0 = wc * 8;
    const int wofs = wr * 32 + ((wc ^ ((wr >> 1) & 3)) * 8);

    const int wave = tid >> 6, lane = tid & 63;
    const int wm = (wave >> 1) * 64, wn = (wave & 1) * 64;
    const int lm = lane & 15, lq = lane >> 4;
    const int rofs = (lq ^ ((lm >> 1) & 3)) * 8;

    f32x4 acc[4][4];
    #pragma unroll
    for (int i = 0; i < 4; ++i)
        #pragma unroll
        for (int j = 0; j < 4; ++j) acc[i][j] = (f32x4){0.f, 0.f, 0.f, 0.f};

    h8v pA0 = *(const h8v*)(A + (size_t)(bm + wr) * K + c0);
    h8v pA1 = *(const h8v*)(A + (size_t)(bm + wr + 64) * K + c0);
    h8v pB0 = *(const h8v*)(Bt + (size_t)(bn + wr) * K + c0);
    h8v pB1 = *(const h8v*)(Bt + (size_t)(bn + wr + 64) * K + c0);

    for (int k0 = 0; k0 < K; k0 += 32) {
        *(h8v*)&sA[wofs] = pA0;  *(h8v*)&sA[wofs + 64 * 32] = pA1;
        *(h8v*)&sB[wofs] = pB0;  *(h8v*)&sB[wofs + 64 * 32] = pB1;
        __syncthreads();

        if (k0 + 32 < K) {
            int kk = k0 + 32 + c0;
            pA0 = *(const h8v*)(A + (size_t)(bm + wr) * K + kk);
            pA1 = *(const h8v*)(A + (size_t)(bm + wr + 64) * K + kk);
            pB0 = *(const h8v*)(Bt + (size_t)(bn + wr) * K + kk);
            pB1 = *(const h8v*)(Bt + (size_t)(bn + wr + 64) * K + kk);
        }

        h8v fa[4], fb[4];
        #pragma unroll
        for (int i = 0; i < 4; ++i) {
            fa[i] = *(const h8v*)&sA[(wm + i * 16 + lm) * 32 + rofs];
            fb[i] = *(const h8v*)&sB[(wn + i * 16 + lm) * 32 + rofs];
        }
        #pragma unroll
        for (int mi = 0; mi < 4; ++mi)
            #pragma unroll
            for (int ni = 0; ni < 4; ++ni)
                acc[mi][ni] = __builtin_amdgcn_mfma_f32_16x16x32_f16(fa[mi], fb[ni], acc[mi][ni], 0, 0, 0);
        __syncthreads();
    }

    // C/D layout: col = lane&15, row = (lane>>4)*4 + reg
    #pragma unroll
    for (int mi = 0; mi < 4; ++mi)
        #pragma unroll
        for (int ni = 0; ni < 4; ++ni) {
            int row = bm + wm + mi * 16 + lq * 4;
            int col = bn + wn + ni * 16 + lm;
            #pragma unroll
            for (int r = 0; r < 4; ++r) {
                float v = acc[mi][ni][r];
                if (EPI == 0) {
                    C[(size_t)(row + r) * ldc + col] = v;
                } else if (EPI == 1) {
                    float a = v + bias[col];
                    C[(size_t)(row + r) * ldc + col] = (a > 20.f) ? a : log1pf(__expf(a));
                } else {
                    if (bn < 2048) {
                        C[(size_t)(row + r) * 2048 + col] = v;
                    } else {
                        float s = v / (1.f + __expf(-v));   // silu(res)
                        H[(size_t)(row + r) * 2048 + (col - 2048)] = (_Float16)s;
                    }
                }
            }
        }
}

// ---------------------------------------------------------------------------
// Skinny fp16 MFMA GEMM for x_dbl: xd[4096][96] = xch[4096][2048] @ WxT[96][2048]^T.
// Block = 64 rows; 4 waves, each 16 rows x 96 cols (6 n-frags). BK=32.
// Same swizzled LDS. Epilogue scatters: 0..63 -> xdh fp16, 64..79 -> Bm, 80..95 -> Cm.
// ---------------------------------------------------------------------------
__global__ __launch_bounds__(256) void gemm_xd(const _Float16* __restrict__ xch,
                                               const _Float16* __restrict__ WxT,
                                               _Float16* __restrict__ xdh,
                                               float* __restrict__ Bm,
                                               float* __restrict__ Cm) {
    __shared__ _Float16 sA[64 * 32];
    __shared__ _Float16 sB[96 * 32];
    const int tid = threadIdx.x;
    const int m0 = blockIdx.x * 64;
    const int wave = tid >> 6, lane = tid & 63;
    const int lm = lane & 15, lq = lane >> 4;
    const int rofs = (lq ^ ((lm >> 1) & 3)) * 8;

    const int wr = tid >> 2, wc = tid & 3, c0 = wc * 8;
    const int wofsA = wr * 32 + ((wc ^ ((wr >> 1) & 3)) * 8);
    const int wr2 = 64 + wr;   // B rows 64..95 staged by tid<128
    const int wofsB2 = wr2 * 32 + ((wc ^ ((wr2 >> 1) & 3)) * 8);

    f32x4 acc[6];
    #pragma unroll
    for (int i = 0; i < 6; ++i) acc[i] = (f32x4){0.f, 0.f, 0.f, 0.f};

    h8v pA = *(const h8v*)(xch + (size_t)(m0 + wr) * D_INNER + c0);
    h8v pB0 = *(const h8v*)(WxT + (size_t)wr * D_INNER + c0);
    h8v pB1 = (tid < 128) ? *(const h8v*)(WxT + (size_t)wr2 * D_INNER + c0) : (h8v)0;

    for (int k0 = 0; k0 < D_INNER; k0 += 32) {
        *(h8v*)&sA[wofsA] = pA;
        *(h8v*)&sB[wofsA] = pB0;
        if (tid < 128) *(h8v*)&sB[wofsB2] = pB1;
        __syncthreads();

        if (k0 + 32 < D_INNER) {
            int kk = k0 + 32 + c0;
            pA = *(const h8v*)(xch + (size_t)(m0 + wr) * D_INNER + kk);
            pB0 = *(const h8v*)(WxT + (size_t)wr * D_INNER + kk);
            if (tid < 128) pB1 = *(const h8v*)(WxT + (size_t)wr2 * D_INNER + kk);
        }

        h8v fa = *(const h8v*)&sA[(wave * 16 + lm) * 32 + rofs];
        #pragma unroll
        for (int nf = 0; nf < 6; ++nf) {
            h8v fb = *(const h8v*)&sB[(nf * 16 + lm) * 32 + rofs];
            acc[nf] = __builtin_amdgcn_mfma_f32_16x16x32_f16(fa, fb, acc[nf], 0, 0, 0);
        }
        __syncthreads();
    }

    #pragma unroll
    for (int nf = 0; nf < 6; ++nf) {
        int col = nf * 16 + lm;
        #pragma unroll
        for (int r = 0; r < 4; ++r) {
            int row = m0 + wave * 16 + lq * 4 + r;
            float v = acc[nf][r];
            if (col < 64)      xdh[(size_t)row * 64 + col] = (_Float16)v;
            else if (col < 80) Bm[(size_t)row * 16 + (col - 64)] = v;
            else               Cm[(size_t)row * 16 + (col - 80)] = v;
        }
    }
}

// ---------------------------------------------------------------------------
// Depthwise causal conv (k=4) + bias + SiLU; reads xs fp32 (ld 2048),
// writes fp16 xch only.
// ---------------------------------------------------------------------------
__global__ __launch_bounds__(256) void conv_silu(const float* __restrict__ xs,
                                                 const float* __restrict__ cw,
                                                 const float* __restrict__ cb,
                                                 _Float16* __restrict__ xch) {
    int idx = blockIdx.x * 256 + threadIdx.x;
    int d = idx & (D_INNER - 1);
    int m = idx >> 11;
    int l = m & (L_SEQ - 1);
    float acc = cb[d];
    #pragma unroll
    for (int k = 0; k < 4; ++k) {
        int ll = l - 3 + k;
        if (ll >= 0)
            acc += xs[(size_t)(m - 3 + k) * D_INNER + d] * cw[d * 4 + k];
    }
    float s = acc / (1.f + __expf(-acc));
    xch[idx] = (_Float16)s;
}

// ---------------------------------------------------------------------------
// Scan pass 1: per (b, chunk, d) chunk-local final state (h0=0) + S=sum(delta).
// 8-deep register prefetch; decay via r^(n+1) power chain when A_log rows are
// log(1..16) (checked at runtime from the loaded values; exp fallback kept).
// ---------------------------------------------------------------------------
__global__ __launch_bounds__(256) void scan_part1(const float* __restrict__ delta,
                                                  const _Float16* __restrict__ xch,
                                                  const float* __restrict__ Bm,
                                                  const float* __restrict__ A_log,
                                                  float* __restrict__ hlocal,
                                                  float* __restrict__ Ssum) {
    const int t = threadIdx.x;
    const int d = blockIdx.x * 256 + t;
    const int c = blockIdx.y;
    const int b = blockIdx.z;

    float An[16];
    {
        const float4* ap = (const float4*)(A_log + (size_t)d * 16);
        #pragma unroll
        for (int q = 0; q < 4; ++q) {
            float4 v = ap[q];
            An[q * 4 + 0] = -__expf(v.x); An[q * 4 + 1] = -__expf(v.y);
            An[q * 4 + 2] = -__expf(v.z); An[q * 4 + 3] = -__expf(v.w);
        }
    }
    const float An0 = An[0];
    bool fast = An0 < 0.f;
    #pragma unroll
    for (int n = 0; n < 16; ++n)
        fast = fast && (fabsf(An[n] - (float)(n + 1) * An0) < 1e-3f * fabsf(An[n]));

    __shared__ float sB[CLEN][16];
    {
        size_t l0 = (size_t)(b * L_SEQ + c * CLEN) * 16;
        #pragma unroll
        for (int i = 0; i < (CLEN * 16) / 256; ++i) {
            int idx = t + i * 256;
            sB[idx >> 4][idx & 15] = Bm[l0 + idx];
        }
    }
    __syncthreads();

    float h[16];
    #pragma unroll
    for (int n = 0; n < 16; ++n) h[n] = 0.f;
    float S = 0.f;

    size_t base = (size_t)(b * L_SEQ + c * CLEN) * D_INNER + d;
    float bd[PFD], bx[PFD];
    #pragma unroll
    for (int i = 0; i < PFD; ++i) {
        bd[i] = delta[base + (size_t)i * D_INNER];
        bx[i] = (float)xch[base + (size_t)i * D_INNER];
    }

    if (fast) {
        for (int jb = 0; jb < CLEN; jb += PFD) {
            #pragma unroll
            for (int i = 0; i < PFD; ++i) {
                int j = jb + i;
                float dv = bd[i], xv = bx[i];
                int jn = j + PFD;
                if (jn < CLEN) {
                    bd[i] = delta[base + (size_t)jn * D_INNER];
                    bx[i] = (float)xch[base + (size_t)jn * D_INNER];
                }
                S += dv;
                float dbx = dv * xv;
                float r = __expf(dv * An0);
                float pw = r;
                #pragma unroll
                for (int n = 0; n < 16; ++n) {
                    h[n] = pw * h[n] + dbx * sB[j][n];
                    pw *= r;
                }
            }
        }
    } else {
        for (int jb = 0; jb < CLEN; jb += PFD) {
            #pragma unroll
            for (int i = 0; i < PFD; ++i) {
                int j = jb + i;
                float dv = bd[i], xv = bx[i];
                int jn = j + PFD;
                if (jn < CLEN) {
                    bd[i] = delta[base + (size_t)jn * D_INNER];
                    bx[i] = (float)xch[base + (size_t)jn * D_INNER];
                }
                S += dv;
                float dbx = dv * xv;
                #pragma unroll
                for (int n = 0; n < 16; ++n)
                    h[n] = __expf(dv * An[n]) * h[n] + dbx * sB[j][n];
            }
        }
    }

    size_t o = ((size_t)(b * NCH + c) * D_INNER + d) * 16;
    float4* hp = (float4*)(hlocal + o);
    #pragma unroll
    for (int q = 0; q < 4; ++q)
        hp[q] = make_float4(h[q * 4], h[q * 4 + 1], h[q * 4 + 2], h[q * 4 + 3]);
    Ssum[(size_t)(b * NCH + c) * D_INNER + d] = S;
}

// ---------------------------------------------------------------------------
// Combine: sequential over NCH chunks per (b,d,n); writes each chunk's h0.
// ---------------------------------------------------------------------------
__global__ __launch_bounds__(256) void scan_combine(const float* __restrict__ hlocal,
                                                    const float* __restrict__ Ssum,
                                                    const float* __restrict__ A_log,
                                                    float* __restrict__ h0buf) {
    int gid = blockIdx.x * 256 + threadIdx.x;
    int n = gid & 15;
    int d = (gid >> 4) & (D_INNER - 1);
    int b = gid >> 15;
    float An = -__expf(A_log[(size_t)d * 16 + n]);
    float H = 0.f;
    float pS[4], pH[4];
    #pragma unroll
    for (int i = 0; i < 4; ++i) {
        size_t sc = (size_t)(b * NCH + i) * D_INNER + d;
        pS[i] = Ssum[sc];
        pH[i] = hlocal[sc * 16 + n];
    }
    for (int cb = 0; cb < NCH; cb += 4) {
        #pragma unroll
        for (int i = 0; i < 4; ++i) {
            int c = cb + i;
            float S = pS[i], hl = pH[i];
            int cn = c + 4;
            if (cn < NCH) {
                size_t sc = (size_t)(b * NCH + cn) * D_INNER + d;
                pS[i] = Ssum[sc];
                pH[i] = hlocal[sc * 16 + n];
            }
            size_t o = ((size_t)(b * NCH + c) * D_INNER + d) * 16 + n;
            h0buf[o] = H;
            H = __expf(An * S) * H + hl;
        }
    }
}

// ---------------------------------------------------------------------------
// Scan pass 2: replay from h0; y = sum_n h*C; fuse +xc*D and *pre-silu'd gate;
// write y as fp16 (A-operand of the output GEMM).
// ---------------------------------------------------------------------------
__global__ __launch_bounds__(256) void scan_part2(const float* __restrict__ delta,
                                                  const _Float16* __restrict__ xch,
                                                  const float* __restrict__ Bm,
                                                  const float* __restrict__ Cm,
                                                  const float* __restrict__ h0buf,
                                                  const float* __restrict__ A_log,
                                                  const float* __restrict__ Dp,
                                                  const _Float16* __restrict__ sresh,
                                                  _Float16* __restrict__ yhalf) {
    const int t = threadIdx.x;
    const int d = blockIdx.x * 256 + t;
    const int c = blockIdx.y;
    const int b = blockIdx.z;

    float An[16];
    {
        const float4* ap = (const float4*)(A_log + (size_t)d * 16);
        #pragma unroll
        for (int q = 0; q < 4; ++q) {
            float4 v = ap[q];
            An[q * 4 + 0] = -__expf(v.x); An[q * 4 + 1] = -__expf(v.y);
            An[q * 4 + 2] = -__expf(v.z); An[q * 4 + 3] = -__expf(v.w);
        }
    }
    const float An0 = An[0];
    bool fast = An0 < 0.f;
    #pragma unroll
    for (int n = 0; n < 16; ++n)
        fast = fast && (fabsf(An[n] - (float)(n + 1) * An0) < 1e-3f * fabsf(An[n]));

    __shared__ float sB[CLEN][16];
    __shared__ float sC[CLEN][16];
    {
        size_t l0 = (size_t)(b * L_SEQ + c * CLEN) * 16;
        #pragma unroll
        for (int i = 0; i < (CLEN * 16) / 256; ++i) {
            int idx = t + i * 256;
            sB[idx >> 4][idx & 15] = Bm[l0 + idx];
            sC[idx >> 4][idx & 15] = Cm[l0 + idx];
        }
    }
    __syncthreads();

    float h[16];
    {
        size_t o = ((size_t)(b * NCH + c) * D_INNER + d) * 16;
        const float4* hp = (const float4*)(h0buf + o);
        #pragma unroll
        for (int q = 0; q < 4; ++q) {
            float4 v = hp[q];
            h[q * 4 + 0] = v.x; h[q * 4 + 1] = v.y;
            h[q * 4 + 2] = v.z; h[q * 4 + 3] = v.w;
        }
    }
    const float Dv = Dp[d];

    size_t base = (size_t)(b * L_SEQ + c * CLEN) * D_INNER + d;
    float bd[PFD], bx[PFD], bg[PFD];
    #pragma unroll
    for (int i = 0; i < PFD; ++i) {
        bd[i] = delta[base + (size_t)i * D_INNER];
        bx[i] = (float)xch[base + (size_t)i * D_INNER];
        bg[i] = (float)sresh[base + (size_t)i * D_INNER];
    }

    if (fast) {
        for (int jb = 0; jb < CLEN; jb += PFD) {
            #pragma unroll
            for (int i = 0; i < PFD; ++i) {
                int j = jb + i;
                float dv = bd[i], xv = bx[i], gv = bg[i];
                int jn = j + PFD;
                if (jn < CLEN) {
                    bd[i] = delta[base + (size_t)jn * D_INNER];
                    bx[i] = (float)xch[base + (size_t)jn * D_INNER];
                    bg[i] = (float)sresh[base + (size_t)jn * D_INNER];
                }
                float dbx = dv * xv;
                float r = __expf(dv * An0);
                float pw = r;
                float y = 0.f;
                #pragma unroll
                for (int n = 0; n < 16; ++n) {
                    h[n] = pw * h[n] + dbx * sB[j][n];
                    y += h[n] * sC[j][n];
                    pw *= r;
                }
                float yv = (y + xv * Dv) * gv;
                yhalf[base + (size_t)j * D_INNER] = (_Float16)yv;
            }
        }
    } else {
        for (int jb = 0; jb < CLEN; jb += PFD) {
            #pragma unroll
            for (int i = 0; i < PFD; ++i) {
                int j = jb + i;
                float dv = bd[i], xv = bx[i], gv = bg[i];
                int jn = j + PFD;
                if (jn < CLEN) {
                    bd[i] = delta[base + (size_t)jn * D_INNER];
                    bx[i] = (float)xch[base + (size_t)jn * D_INNER];
                    bg[i] = (float)sresh[base + (size_t)jn * D_INNER];
                }
                float dbx = dv * xv;
                float y = 0.f;
                #pragma unroll
                for (int n = 0; n < 16; ++n) {
                    h[n] = __expf(dv * An[n]) * h[n] + dbx * sB[j][n];
                    y += h[n] * sC[j][n];
                }
                float yv = (y + xv * Dv) * gv;
                yhalf[base + (size_t)j * D_INNER] = (_Float16)yv;
            }
        }
    }
}

extern "C" void kernel_launch(void* const* d_in, const int* in_sizes, int n_in,
                              void* d_out, int out_size, void* d_ws, size_t ws_size,
                              hipStream_t stream) {
    const float* x      = (const float*)d_in[0];
    const float* W_in   = (const float*)d_in[1];
    const float* conv_w = (const float*)d_in[2];
    const float* conv_b = (const float*)d_in[3];
    const float* W_x    = (const float*)d_in[4];
    const float* W_dt   = (const float*)d_in[5];
    const float* b_dt   = (const float*)d_in[6];
    const float* A_log  = (const float*)d_in[7];
    const float* D_par  = (const float*)d_in[8];
    const float* W_out  = (const float*)d_in[9];
    float* out = (float*)d_out;

    char* wsb = (char*)d_ws;
    float*     xs    = (float*)(wsb + 0);               //  33,554,432 B
    _Float16*  sresh = (_Float16*)(wsb + 33554432);     //  16,777,216 B (silu(res) fp16)
    float*     delta = (float*)(wsb + 50331648);        //  33,554,432 B
    _Float16*  xch   = (_Float16*)(wsb + 83886080);     //  16,777,216 B
    _Float16*  xf16  = (_Float16*)(wsb + 100663296);    //   8,388,608 B (dead after K1)
    _Float16*  WinT  = (_Float16*)(wsb + 109051904);    //   8,388,608 B (dead after K1)
    _Float16*  yhalf = (_Float16*)(wsb + 100663296);    //  16,777,216 B (aliases xf16+WinT)
    _Float16*  WxT   = (_Float16*)(wsb + 117440512);    //     393,216 B
    _Float16*  xdh   = (_Float16*)(wsb + 117833728);    //     524,288 B
    _Float16*  WdtT  = (_Float16*)(wsb + 118358016);    //     262,144 B
    float*     Bbuf  = (float*)(wsb + 118620160);       //     262,144 B
    float*     Cbuf  = (float*)(wsb + 118882304);       //     262,144 B
    float*     Ssum  = (float*)(wsb + 119144448);       //   1,048,576 B
    float*     hloc  = (float*)(wsb + 120193024);       //  16,777,216 B
    float*     h0buf = (float*)(wsb + 136970240);       //  16,777,216 B
    _Float16*  WoutT = (_Float16*)(wsb + 153747456);    //   4,194,304 B
    // end: 157,941,760 B

    dim3 blk(256);

    // 1. x -> fp16
    cast_f16<<<dim3((MM * D_MODEL / 4) / 256), blk, 0, stream>>>(x, xf16, MM * D_MODEL / 4);
    // 2. W_in [1024][4096] -> fp16 transposed [4096][1024]
    transpose_f16<<<dim3(4096 / 32, 1024 / 32), blk, 0, stream>>>(W_in, WinT, D_MODEL, 2 * D_INNER);
    // 3. K1: [xs | silu(res)] = x @ W_in  (M=4096, N=4096, K=1024), split store
    gemm_f16<2><<<dim3(32, 32), blk, 0, stream>>>(xf16, WinT, nullptr, xs, sresh, MM, 2 * D_INNER, D_MODEL, 2048);
    // 4. conv + SiLU -> xch fp16
    conv_silu<<<dim3((size_t)MM * D_INNER / 256), blk, 0, stream>>>(xs, conv_w, conv_b, xch);
    // 5. W_x [2048][96] -> fp16 transposed [96][2048]
    transpose_f16<<<dim3(96 / 32, 2048 / 32), blk, 0, stream>>>(W_x, WxT, D_INNER, 96);
    // 6. xd = xc @ W_x (skinny): xdh fp16 + B, C fp32
    gemm_xd<<<dim3(MM / 64), blk, 0, stream>>>(xch, WxT, xdh, Bbuf, Cbuf);
    // 7. W_dt [64][2048] -> fp16 transposed [2048][64]
    transpose_f16<<<dim3(2048 / 32, 64 / 32), blk, 0, stream>>>(W_dt, WdtT, DT_RANK, D_INNER);
    // 8. delta = softplus(xd @ W_dt + b_dt)  (M=4096, N=2048, K=64)
    gemm_f16<1><<<dim3(16, 32), blk, 0, stream>>>(xdh, WdtT, b_dt, delta, nullptr, MM, D_INNER, DT_RANK, D_INNER);
    // 9. scan pass 1
    scan_part1<<<dim3(D_INNER / 256, NCH, B_SZ), blk, 0, stream>>>(delta, xch, Bbuf, A_log, hloc, Ssum);
    // 10. combine
    scan_combine<<<dim3(B_SZ * D_INNER * 16 / 256), blk, 0, stream>>>(hloc, Ssum, A_log, h0buf);
    // 11. W_out [2048][1024] -> fp16 transposed [1024][2048]
    transpose_f16<<<dim3(1024 / 32, 2048 / 32), blk, 0, stream>>>(W_out, WoutT, D_INNER, D_MODEL);
    // 12. scan pass 2 (+gating) -> yhalf fp16
    scan_part2<<<dim3(D_INNER / 256, NCH, B_SZ), blk, 0, stream>>>(delta, xch, Bbuf, Cbuf, h0buf, A_log, D_par, sresh, yhalf);
    // 13. K5: out = y @ W_out  (M=4096, N=1024, K=2048)
    gemm_f16<0><<<dim3(8, 32), blk, 0, stream>>>(yhalf, WoutT, nullptr, out, nullptr, MM, D_MODEL, D_INNER, D_MODEL);
}

// Round 6
// 358.241 us; speedup vs baseline: 7.7169x; 1.0165x over previous
//
#include <hip/hip_runtime.h>
#include <math.h>

#define B_SZ    2
#define L_SEQ   2048
#define D_MODEL 1024
#define D_INNER 2048
#define D_STATE 16
#define DT_RANK 64
#define MM      (B_SZ * L_SEQ)   // 4096 rows
#define NCH     64               // scan chunks
#define CLEN    (L_SEQ / NCH)    // 32 steps per chunk
#define PFD     8                // scan prefetch depth

typedef _Float16 h8v __attribute__((ext_vector_type(8)));
typedef _Float16 h4v __attribute__((ext_vector_type(4)));
typedef float f32x4 __attribute__((ext_vector_type(4)));

// Async global->LDS DMA, 16B per lane. LDS dest = uniform base + lane*16.
__device__ __forceinline__ void gload16(const void* g, void* l) {
    __builtin_amdgcn_global_load_lds((const __attribute__((address_space(1))) void*)g,
                                     (__attribute__((address_space(3))) void*)l, 16, 0, 0);
}

// ---------------------------------------------------------------------------
// prep: all weight transposes (fp32 -> fp16 T[N][K]) + x -> fp16 cast, fused
// into one dispatch. Tile ranges are compile-time constants.
//   J0 W_in  K=1024 N=4096 : tiles 128x32 = 4096   [0, 4096)
//   J1 W_x   K=2048 N=96   : tiles   3x64 = 192    [4096, 4288)
//   J2 W_dt  K=64   N=2048 : tiles  64x2  = 128    [4288, 4416)
//   J3 W_out K=2048 N=1024 : tiles  32x64 = 2048   [4416, 6464)
//   J4 cast x (4096x1024)  : 4096 blocks           [6464, 10560)
// ---------------------------------------------------------------------------
__global__ __launch_bounds__(256) void prep(const float* __restrict__ x,
                                            _Float16* __restrict__ xf16,
                                            const float* __restrict__ W_in,
                                            _Float16* __restrict__ WinT,
                                            const float* __restrict__ W_x,
                                            _Float16* __restrict__ WxT,
                                            const float* __restrict__ W_dt,
                                            _Float16* __restrict__ WdtT,
                                            const float* __restrict__ W_out,
                                            _Float16* __restrict__ WoutT) {
    __shared__ float t[32][33];
    const int b = blockIdx.x;
    const float* W; _Float16* T; int K, N, tile;
    if (b < 4096)      { W = W_in;  T = WinT;  K = 1024; N = 4096; tile = b; }
    else if (b < 4288) { W = W_x;   T = WxT;   K = 2048; N = 96;   tile = b - 4096; }
    else if (b < 4416) { W = W_dt;  T = WdtT;  K = 64;   N = 2048; tile = b - 4288; }
    else if (b < 6464) { W = W_out; T = WoutT; K = 2048; N = 1024; tile = b - 4416; }
    else {
        int idx = (b - 6464) * 256 + threadIdx.x;
        float4 v = ((const float4*)x)[idx];
        h4v h = {(_Float16)v.x, (_Float16)v.y, (_Float16)v.z, (_Float16)v.w};
        *(h4v*)(xf16 + (size_t)idx * 4) = h;
        return;
    }
    const int ntx = N / 32;
    const int k0 = (tile / ntx) * 32, n0 = (tile % ntx) * 32;
    #pragma unroll
    for (int i = 0; i < 4; ++i) {
        int idx = threadIdx.x + i * 256;
        int r = idx >> 5, c = idx & 31;
        t[r][c] = W[(size_t)(k0 + r) * N + n0 + c];
    }
    __syncthreads();
    #pragma unroll
    for (int i = 0; i < 4; ++i) {
        int idx = threadIdx.x + i * 256;
        int n = idx >> 5, k = idx & 31;
        T[(size_t)(n0 + n) * K + k0 + k] = (_Float16)t[k][n];
    }
}

// ---------------------------------------------------------------------------
// fp16 MFMA GEMM, async-staged (m97 structure): C = A[M][K] @ Bt[N][K]^T.
// Block tile 128 x NT, 256 thr. NT=128: 4 waves 2x2, wave 64x64 (4x4 frags).
// NT=64: 4 waves stacked on M, wave 32x64 (2x4 frags) -- 2x the blocks for
// small-N shapes so other blocks hide the barrier vmcnt drain.
// LDS is XOR-swizzled at 16B granularity via the *global source* address per
// lane (DMA dest is lane-contiguous): position (r,p) holds chunk p^((r>>1)&3)
// -> both DMA writes and ds_read_b128 frag reads are conflict-free (quarter-
// wave phasing, 2-way free per m136).
// EPI 0: fp32 C. EPI 1: fp16 H = softplus(acc+bias[col]) (delta).
// EPI 2: cols<2048 -> fp16 H (xs); cols>=2048 -> fp16 Hg = silu (res gate).
// ---------------------------------------------------------------------------
template<int EPI, int NT>
__global__ __launch_bounds__(256) void gemm_f16(const _Float16* __restrict__ A,
                                                const _Float16* __restrict__ Bt,
                                                const float* __restrict__ bias,
                                                float* __restrict__ C,
                                                _Float16* __restrict__ H,
                                                _Float16* __restrict__ Hg,
                                                int M, int N, int K, int ldc) {
    __shared__ _Float16 sA[128 * 32];
    __shared__ _Float16 sB[NT * 32];

    const int tid = threadIdx.x;
    const int wave = tid >> 6, lane = tid & 63;
    const int bm = blockIdx.y * 128, bn = blockIdx.x * NT;

    const int lrow = lane >> 2, pc = lane & 3;

    // A staging: wave stages rows [wave*32, +32) as two 16-row DMAs.
    const int ar = wave * 32 + lrow;
    const size_t gA = (size_t)(bm + ar) * K + ((pc ^ ((ar >> 1) & 3)) * 8);
    _Float16* lA0 = sA + (wave * 32) * 32;
    _Float16* lA1 = sA + (wave * 32 + 16) * 32;
    // B staging: wave stages rows [wave*(NT/4), +NT/4).
    const int br = wave * (NT / 4) + lrow;
    const size_t gB = (size_t)(bn + br) * K + ((pc ^ ((br >> 1) & 3)) * 8);
    _Float16* lB0 = sB + (wave * (NT / 4)) * 32;
    _Float16* lB1 = sB + (wave * (NT / 4) + 16) * 32;

    const int lm = lane & 15, lq = lane >> 4;
    const int rofs = (lq ^ ((lm >> 1) & 3)) * 8;
    constexpr int MI = (NT == 128) ? 4 : 2;
    const int wm = (NT == 128) ? (wave >> 1) * 64 : wave * 32;
    const int wn = (NT == 128) ? (wave & 1) * 64 : 0;

    f32x4 acc[MI][4];
    #pragma unroll
    for (int i = 0; i < MI; ++i)
        #pragma unroll
        for (int j = 0; j < 4; ++j) acc[i][j] = (f32x4){0.f, 0.f, 0.f, 0.f};

    for (int k0 = 0; k0 < K; k0 += 32) {
        gload16(A + gA + k0, lA0);
        gload16(A + gA + k0 + (size_t)16 * K, lA1);
        gload16(Bt + gB + k0, lB0);
        if (NT == 128) gload16(Bt + gB + k0 + (size_t)16 * K, lB1);
        __syncthreads();   // drains DMA (vmcnt) + joins compute

        h8v fa[MI], fb[4];
        #pragma unroll
        for (int i = 0; i < MI; ++i)
            fa[i] = *(const h8v*)&sA[(wm + i * 16 + lm) * 32 + rofs];
        #pragma unroll
        for (int i = 0; i < 4; ++i)
            fb[i] = *(const h8v*)&sB[(wn + i * 16 + lm) * 32 + rofs];
        #pragma unroll
        for (int mi = 0; mi < MI; ++mi)
            #pragma unroll
            for (int ni = 0; ni < 4; ++ni)
                acc[mi][ni] = __builtin_amdgcn_mfma_f32_16x16x32_f16(fa[mi], fb[ni], acc[mi][ni], 0, 0, 0);
        __syncthreads();
    }

    // C/D layout: col = lane&15, row = (lane>>4)*4 + reg
    #pragma unroll
    for (int mi = 0; mi < MI; ++mi)
        #pragma unroll
        for (int ni = 0; ni < 4; ++ni) {
            int row = bm + wm + mi * 16 + lq * 4;
            int col = bn + wn + ni * 16 + lm;
            #pragma unroll
            for (int r = 0; r < 4; ++r) {
                float v = acc[mi][ni][r];
                if (EPI == 0) {
                    C[(size_t)(row + r) * ldc + col] = v;
                } else if (EPI == 1) {
                    float a = v + bias[col];
                    H[(size_t)(row + r) * ldc + col] =
                        (_Float16)((a > 20.f) ? a : log1pf(__expf(a)));
                } else {
                    if (bn < 2048) {
                        H[(size_t)(row + r) * 2048 + col] = (_Float16)v;
                    } else {
                        float s = v / (1.f + __expf(-v));   // silu(res)
                        Hg[(size_t)(row + r) * 2048 + (col - 2048)] = (_Float16)s;
                    }
                }
            }
        }
}

// ---------------------------------------------------------------------------
// Skinny fp16 MFMA GEMM for x_dbl: xd[4096][96] = xch @ WxT^T. 64 rows/block,
// 4 waves x 16 rows x 96 cols. Register-prefetch staging (kernel is tiny).
// Epilogue scatters: 0..63 -> xdh fp16, 64..79 -> Bm, 80..95 -> Cm.
// ---------------------------------------------------------------------------
__global__ __launch_bounds__(256) void gemm_xd(const _Float16* __restrict__ xch,
                                               const _Float16* __restrict__ WxT,
                                               _Float16* __restrict__ xdh,
                                               float* __restrict__ Bm,
                                               float* __restrict__ Cm) {
    __shared__ _Float16 sA[64 * 32];
    __shared__ _Float16 sB[96 * 32];
    const int tid = threadIdx.x;
    const int m0 = blockIdx.x * 64;
    const int wave = tid >> 6, lane = tid & 63;
    const int lm = lane & 15, lq = lane >> 4;
    const int rofs = (lq ^ ((lm >> 1) & 3)) * 8;

    const int wr = tid >> 2, wc = tid & 3, c0 = wc * 8;
    const int wofsA = wr * 32 + ((wc ^ ((wr >> 1) & 3)) * 8);
    const int wr2 = 64 + wr;
    const int wofsB2 = wr2 * 32 + ((wc ^ ((wr2 >> 1) & 3)) * 8);

    f32x4 acc[6];
    #pragma unroll
    for (int i = 0; i < 6; ++i) acc[i] = (f32x4){0.f, 0.f, 0.f, 0.f};

    h8v pA = *(const h8v*)(xch + (size_t)(m0 + wr) * D_INNER + c0);
    h8v pB0 = *(const h8v*)(WxT + (size_t)wr * D_INNER + c0);
    h8v pB1 = (tid < 128) ? *(const h8v*)(WxT + (size_t)wr2 * D_INNER + c0) : (h8v)0;

    for (int k0 = 0; k0 < D_INNER; k0 += 32) {
        *(h8v*)&sA[wofsA] = pA;
        *(h8v*)&sB[wofsA] = pB0;
        if (tid < 128) *(h8v*)&sB[wofsB2] = pB1;
        __syncthreads();

        if (k0 + 32 < D_INNER) {
            int kk = k0 + 32 + c0;
            pA = *(const h8v*)(xch + (size_t)(m0 + wr) * D_INNER + kk);
            pB0 = *(const h8v*)(WxT + (size_t)wr * D_INNER + kk);
            if (tid < 128) pB1 = *(const h8v*)(WxT + (size_t)wr2 * D_INNER + kk);
        }

        h8v fa = *(const h8v*)&sA[(wave * 16 + lm) * 32 + rofs];
        #pragma unroll
        for (int nf = 0; nf < 6; ++nf) {
            h8v fb = *(const h8v*)&sB[(nf * 16 + lm) * 32 + rofs];
            acc[nf] = __builtin_amdgcn_mfma_f32_16x16x32_f16(fa, fb, acc[nf], 0, 0, 0);
        }
        __syncthreads();
    }

    #pragma unroll
    for (int nf = 0; nf < 6; ++nf) {
        int col = nf * 16 + lm;
        #pragma unroll
        for (int r = 0; r < 4; ++r) {
            int row = m0 + wave * 16 + lq * 4 + r;
            float v = acc[nf][r];
            if (col < 64)      xdh[(size_t)row * 64 + col] = (_Float16)v;
            else if (col < 80) Bm[(size_t)row * 16 + (col - 64)] = v;
            else               Cm[(size_t)row * 16 + (col - 80)] = v;
        }
    }
}

// ---------------------------------------------------------------------------
// Depthwise causal conv (k=4) + bias + SiLU. Reads fp16 xs, writes fp16 xch.
// ---------------------------------------------------------------------------
__global__ __launch_bounds__(256) void conv_silu(const _Float16* __restrict__ xsh,
                                                 const float* __restrict__ cw,
                                                 const float* __restrict__ cb,
                                                 _Float16* __restrict__ xch) {
    int idx = blockIdx.x * 256 + threadIdx.x;
    int d = idx & (D_INNER - 1);
    int m = idx >> 11;
    int l = m & (L_SEQ - 1);
    float acc = cb[d];
    #pragma unroll
    for (int k = 0; k < 4; ++k) {
        int ll = l - 3 + k;
        if (ll >= 0)
            acc += (float)xsh[(size_t)(m - 3 + k) * D_INNER + d] * cw[d * 4 + k];
    }
    float s = acc / (1.f + __expf(-acc));
    xch[idx] = (_Float16)s;
}

// ---------------------------------------------------------------------------
// Scan pass 1: per (b, chunk, d) chunk-local final state (h0=0) + S=sum(delta).
// 8-deep register prefetch; r^(n+1) power-chain decay when A_log rows are
// log(1..16) (runtime-checked from loaded values; exp fallback kept).
// ---------------------------------------------------------------------------
__global__ __launch_bounds__(256) void scan_part1(const _Float16* __restrict__ deltah,
                                                  const _Float16* __restrict__ xch,
                                                  const float* __restrict__ Bm,
                                                  const float* __restrict__ A_log,
                                                  float* __restrict__ hlocal,
                                                  float* __restrict__ Ssum) {
    const int t = threadIdx.x;
    const int d = blockIdx.x * 256 + t;
    const int c = blockIdx.y;
    const int b = blockIdx.z;

    float An[16];
    {
        const float4* ap = (const float4*)(A_log + (size_t)d * 16);
        #pragma unroll
        for (int q = 0; q < 4; ++q) {
            float4 v = ap[q];
            An[q * 4 + 0] = -__expf(v.x); An[q * 4 + 1] = -__expf(v.y);
            An[q * 4 + 2] = -__expf(v.z); An[q * 4 + 3] = -__expf(v.w);
        }
    }
    const float An0 = An[0];
    bool fast = An0 < 0.f;
    #pragma unroll
    for (int n = 0; n < 16; ++n)
        fast = fast && (fabsf(An[n] - (float)(n + 1) * An0) < 1e-3f * fabsf(An[n]));

    __shared__ float sB[CLEN][16];
    {
        size_t l0 = (size_t)(b * L_SEQ + c * CLEN) * 16;
        #pragma unroll
        for (int i = 0; i < (CLEN * 16) / 256; ++i) {
            int idx = t + i * 256;
            sB[idx >> 4][idx & 15] = Bm[l0 + idx];
        }
    }
    __syncthreads();

    float h[16];
    #pragma unroll
    for (int n = 0; n < 16; ++n) h[n] = 0.f;
    float S = 0.f;

    size_t base = (size_t)(b * L_SEQ + c * CLEN) * D_INNER + d;
    float bd[PFD], bx[PFD];
    #pragma unroll
    for (int i = 0; i < PFD; ++i) {
        bd[i] = (float)deltah[base + (size_t)i * D_INNER];
        bx[i] = (float)xch[base + (size_t)i * D_INNER];
    }

    if (fast) {
        for (int jb = 0; jb < CLEN; jb += PFD) {
            #pragma unroll
            for (int i = 0; i < PFD; ++i) {
                int j = jb + i;
                float dv = bd[i], xv = bx[i];
                int jn = j + PFD;
                if (jn < CLEN) {
                    bd[i] = (float)deltah[base + (size_t)jn * D_INNER];
                    bx[i] = (float)xch[base + (size_t)jn * D_INNER];
                }
                S += dv;
                float dbx = dv * xv;
                float r = __expf(dv * An0);
                float pw = r;
                #pragma unroll
                for (int n = 0; n < 16; ++n) {
                    h[n] = pw * h[n] + dbx * sB[j][n];
                    pw *= r;
                }
            }
        }
    } else {
        for (int jb = 0; jb < CLEN; jb += PFD) {
            #pragma unroll
            for (int i = 0; i < PFD; ++i) {
                int j = jb + i;
                float dv = bd[i], xv = bx[i];
                int jn = j + PFD;
                if (jn < CLEN) {
                    bd[i] = (float)deltah[base + (size_t)jn * D_INNER];
                    bx[i] = (float)xch[base + (size_t)jn * D_INNER];
                }
                S += dv;
                float dbx = dv * xv;
                #pragma unroll
                for (int n = 0; n < 16; ++n)
                    h[n] = __expf(dv * An[n]) * h[n] + dbx * sB[j][n];
            }
        }
    }

    size_t o = ((size_t)(b * NCH + c) * D_INNER + d) * 16;
    float4* hp = (float4*)(hlocal + o);
    #pragma unroll
    for (int q = 0; q < 4; ++q)
        hp[q] = make_float4(h[q * 4], h[q * 4 + 1], h[q * 4 + 2], h[q * 4 + 3]);
    Ssum[(size_t)(b * NCH + c) * D_INNER + d] = S;
}

// ---------------------------------------------------------------------------
// Combine: sequential over NCH chunks per (b,d,n); writes each chunk's h0.
// ---------------------------------------------------------------------------
__global__ __launch_bounds__(256) void scan_combine(const float* __restrict__ hlocal,
                                                    const float* __restrict__ Ssum,
                                                    const float* __restrict__ A_log,
                                                    float* __restrict__ h0buf) {
    int gid = blockIdx.x * 256 + threadIdx.x;
    int n = gid & 15;
    int d = (gid >> 4) & (D_INNER - 1);
    int b = gid >> 15;
    float An = -__expf(A_log[(size_t)d * 16 + n]);
    float H = 0.f;
    float pS[4], pH[4];
    #pragma unroll
    for (int i = 0; i < 4; ++i) {
        size_t sc = (size_t)(b * NCH + i) * D_INNER + d;
        pS[i] = Ssum[sc];
        pH[i] = hlocal[sc * 16 + n];
    }
    for (int cb = 0; cb < NCH; cb += 4) {
        #pragma unroll
        for (int i = 0; i < 4; ++i) {
            int c = cb + i;
            float S = pS[i], hl = pH[i];
            int cn = c + 4;
            if (cn < NCH) {
                size_t sc = (size_t)(b * NCH + cn) * D_INNER + d;
                pS[i] = Ssum[sc];
                pH[i] = hlocal[sc * 16 + n];
            }
            size_t o = ((size_t)(b * NCH + c) * D_INNER + d) * 16 + n;
            h0buf[o] = H;
            H = __expf(An * S) * H + hl;
        }
    }
}

// ---------------------------------------------------------------------------
// Scan pass 2: replay from h0; y = sum_n h*C; fuse +xc*D and *pre-silu'd gate;
// write y fp16 (A-operand of the output GEMM).
// ---------------------------------------------------------------------------
__global__ __launch_bounds__(256) void scan_part2(const _Float16* __restrict__ deltah,
                                                  const _Float16* __restrict__ xch,
                                                  const float* __restrict__ Bm,
                                                  const float* __restrict__ Cm,
                                                  const float* __restrict__ h0buf,
                                                  const float* __restrict__ A_log,
                                                  const float* __restrict__ Dp,
                                                  const _Float16* __restrict__ sresh,
                                                  _Float16* __restrict__ yhalf) {
    const int t = threadIdx.x;
    const int d = blockIdx.x * 256 + t;
    const int c = blockIdx.y;
    const int b = blockIdx.z;

    float An[16];
    {
        const float4* ap = (const float4*)(A_log + (size_t)d * 16);
        #pragma unroll
        for (int q = 0; q < 4; ++q) {
            float4 v = ap[q];
            An[q * 4 + 0] = -__expf(v.x); An[q * 4 + 1] = -__expf(v.y);
            An[q * 4 + 2] = -__expf(v.z); An[q * 4 + 3] = -__expf(v.w);
        }
    }
    const float An0 = An[0];
    bool fast = An0 < 0.f;
    #pragma unroll
    for (int n = 0; n < 16; ++n)
        fast = fast && (fabsf(An[n] - (float)(n + 1) * An0) < 1e-3f * fabsf(An[n]));

    __shared__ float sB[CLEN][16];
    __shared__ float sC[CLEN][16];
    {
        size_t l0 = (size_t)(b * L_SEQ + c * CLEN) * 16;
        #pragma unroll
        for (int i = 0; i < (CLEN * 16) / 256; ++i) {
            int idx = t + i * 256;
            sB[idx >> 4][idx & 15] = Bm[l0 + idx];
            sC[idx >> 4][idx & 15] = Cm[l0 + idx];
        }
    }
    __syncthreads();

    float h[16];
    {
        size_t o = ((size_t)(b * NCH + c) * D_INNER + d) * 16;
        const float4* hp = (const float4*)(h0buf + o);
        #pragma unroll
        for (int q = 0; q < 4; ++q) {
            float4 v = hp[q];
            h[q * 4 + 0] = v.x; h[q * 4 + 1] = v.y;
            h[q * 4 + 2] = v.z; h[q * 4 + 3] = v.w;
        }
    }
    const float Dv = Dp[d];

    size_t base = (size_t)(b * L_SEQ + c * CLEN) * D_INNER + d;
    float bd[PFD], bx[PFD], bg[PFD];
    #pragma unroll
    for (int i = 0; i < PFD; ++i) {
        bd[i] = (float)deltah[base + (size_t)i * D_INNER];
        bx[i] = (float)xch[base + (size_t)i * D_INNER];
        bg[i] = (float)sresh[base + (size_t)i * D_INNER];
    }

    if (fast) {
        for (int jb = 0; jb < CLEN; jb += PFD) {
            #pragma unroll
            for (int i = 0; i < PFD; ++i) {
                int j = jb + i;
                float dv = bd[i], xv = bx[i], gv = bg[i];
                int jn = j + PFD;
                if (jn < CLEN) {
                    bd[i] = (float)deltah[base + (size_t)jn * D_INNER];
                    bx[i] = (float)xch[base + (size_t)jn * D_INNER];
                    bg[i] = (float)sresh[base + (size_t)jn * D_INNER];
                }
                float dbx = dv * xv;
                float r = __expf(dv * An0);
                float pw = r;
                float y = 0.f;
                #pragma unroll
                for (int n = 0; n < 16; ++n) {
                    h[n] = pw * h[n] + dbx * sB[j][n];
                    y += h[n] * sC[j][n];
                    pw *= r;
                }
                float yv = (y + xv * Dv) * gv;
                yhalf[base + (size_t)j * D_INNER] = (_Float16)yv;
            }
        }
    } else {
        for (int jb = 0; jb < CLEN; jb += PFD) {
            #pragma unroll
            for (int i = 0; i < PFD; ++i) {
                int j = jb + i;
                float dv = bd[i], xv = bx[i], gv = bg[i];
                int jn = j + PFD;
                if (jn < CLEN) {
                    bd[i] = (float)deltah[base + (size_t)jn * D_INNER];
                    bx[i] = (float)xch[base + (size_t)jn * D_INNER];
                    bg[i] = (float)sresh[base + (size_t)jn * D_INNER];
                }
                float dbx = dv * xv;
                float y = 0.f;
                #pragma unroll
                for (int n = 0; n < 16; ++n) {
                    h[n] = __expf(dv * An[n]) * h[n] + dbx * sB[j][n];
                    y += h[n] * sC[j][n];
                }
                float yv = (y + xv * Dv) * gv;
                yhalf[base + (size_t)j * D_INNER] = (_Float16)yv;
            }
        }
    }
}

extern "C" void kernel_launch(void* const* d_in, const int* in_sizes, int n_in,
                              void* d_out, int out_size, void* d_ws, size_t ws_size,
                              hipStream_t stream) {
    const float* x      = (const float*)d_in[0];
    const float* W_in   = (const float*)d_in[1];
    const float* conv_w = (const float*)d_in[2];
    const float* conv_b = (const float*)d_in[3];
    const float* W_x    = (const float*)d_in[4];
    const float* W_dt   = (const float*)d_in[5];
    const float* b_dt   = (const float*)d_in[6];
    const float* A_log  = (const float*)d_in[7];
    const float* D_par  = (const float*)d_in[8];
    const float* W_out  = (const float*)d_in[9];
    float* out = (float*)d_out;

    char* wsb = (char*)d_ws;
    _Float16*  xsh    = (_Float16*)(wsb + 0);             // 16,777,216 B (xs fp16)
    _Float16*  sresh  = (_Float16*)(wsb + 16777216);      // 16,777,216 B (silu(res))
    _Float16*  deltah = (_Float16*)(wsb + 33554432);      // 16,777,216 B
    _Float16*  xch    = (_Float16*)(wsb + 50331648);      // 16,777,216 B
    _Float16*  xf16   = (_Float16*)(wsb + 67108864);      //  8,388,608 B (dead after K1)
    _Float16*  WinT   = (_Float16*)(wsb + 75497472);      //  8,388,608 B (dead after K1)
    _Float16*  yhalf  = (_Float16*)(wsb + 67108864);      // 16,777,216 B (aliases xf16+WinT)
    _Float16*  WxT    = (_Float16*)(wsb + 83886080);      //    393,216 B
    _Float16*  xdh    = (_Float16*)(wsb + 84279296);      //    524,288 B
    _Float16*  WdtT   = (_Float16*)(wsb + 84803584);      //    262,144 B
    float*     Bbuf   = (float*)(wsb + 85065728);         //    262,144 B
    float*     Cbuf   = (float*)(wsb + 85327872);         //    262,144 B
    float*     Ssum   = (float*)(wsb + 85590016);         //  1,048,576 B
    float*     hloc   = (float*)(wsb + 86638592);         // 16,777,216 B
    float*     h0buf  = (float*)(wsb + 103415808);        // 16,777,216 B
    _Float16*  WoutT  = (_Float16*)(wsb + 120193024);     //  4,194,304 B
    // end: 124,387,328 B

    dim3 blk(256);

    // 1. fused prep: all weight transposes + x cast
    prep<<<dim3(10560), blk, 0, stream>>>(x, xf16, W_in, WinT, W_x, WxT,
                                          W_dt, WdtT, W_out, WoutT);
    // 2. K1: [xs fp16 | silu(res) fp16] = x @ W_in  (M=4096, N=4096, K=1024)
    gemm_f16<2, 128><<<dim3(32, 32), blk, 0, stream>>>(
        xf16, WinT, nullptr, nullptr, xsh, sresh, MM, 2 * D_INNER, D_MODEL, 2048);
    // 3. conv + SiLU -> xch fp16
    conv_silu<<<dim3((size_t)MM * D_INNER / 256), blk, 0, stream>>>(xsh, conv_w, conv_b, xch);
    // 4. xd = xc @ W_x (skinny): xdh fp16 + B, C fp32
    gemm_xd<<<dim3(MM / 64), blk, 0, stream>>>(xch, WxT, xdh, Bbuf, Cbuf);
    // 5. delta = softplus(xd @ W_dt + b_dt) -> fp16  (M=4096, N=2048, K=64)
    gemm_f16<1, 128><<<dim3(16, 32), blk, 0, stream>>>(
        xdh, WdtT, b_dt, nullptr, deltah, nullptr, MM, D_INNER, DT_RANK, D_INNER);
    // 6. scan pass 1
    scan_part1<<<dim3(D_INNER / 256, NCH, B_SZ), blk, 0, stream>>>(deltah, xch, Bbuf, A_log, hloc, Ssum);
    // 7. combine
    scan_combine<<<dim3(B_SZ * D_INNER * 16 / 256), blk, 0, stream>>>(hloc, Ssum, A_log, h0buf);
    // 8. scan pass 2 (+gating) -> yhalf fp16
    scan_part2<<<dim3(D_INNER / 256, NCH, B_SZ), blk, 0, stream>>>(deltah, xch, Bbuf, Cbuf, h0buf, A_log, D_par, sresh, yhalf);
    // 9. K5: out = y @ W_out  (M=4096, N=1024, K=2048), 128x64 tile -> 512 blocks
    gemm_f16<0, 64><<<dim3(16, 32), blk, 0, stream>>>(
        yhalf, WoutT, nullptr, out, nullptr, nullptr, MM, D_MODEL, D_INNER, D_MODEL);
}